// Round 1
// baseline (403.718 us; speedup 1.0000x reference)
//
#include <hip/hip_runtime.h>

typedef __bf16 bf16x8 __attribute__((ext_vector_type(8)));
typedef float f32x4 __attribute__((ext_vector_type(4)));

#define PI_F 3.14159265358979323846f

__device__ __forceinline__ unsigned short f2bf(float f) {
  unsigned u = __builtin_bit_cast(unsigned, f);
  u += 0x7fffu + ((u >> 16) & 1u);
  return (unsigned short)(u >> 16);
}

__device__ __forceinline__ unsigned scale_pair(unsigned w, float f) {
  const float lo = __builtin_bit_cast(float, w << 16);
  const float hi = __builtin_bit_cast(float, w & 0xffff0000u);
  return (unsigned)f2bf(lo * f) | ((unsigned)f2bf(hi * f) << 16);
}

#define GLD16(gp, lp)                                          \
  __builtin_amdgcn_global_load_lds(                            \
      (const __attribute__((address_space(1))) void*)(gp),     \
      (__attribute__((address_space(3))) void*)(lp), 16, 0, 0)

// ---------------- k1: fp32 -> bf16 conversion ----------------
__global__ __launch_bounds__(256) void convert_all(
    const float* __restrict__ q, const float* __restrict__ k, const float* __restrict__ v,
    const float* __restrict__ Wq, const float* __restrict__ Wk,
    const float* __restrict__ Wv, const float* __restrict__ Wo,
    unsigned short* __restrict__ qb, unsigned short* __restrict__ kb,
    unsigned short* __restrict__ vb, unsigned short* __restrict__ Wqb,
    unsigned short* __restrict__ Wkb, unsigned short* __restrict__ Wvb,
    unsigned short* __restrict__ Wob) {
  const int region = blockIdx.y;
  const float* s; unsigned short* d; int n4;
  switch (region) {
    case 0: s = q;  d = qb;  n4 = 4194304; break;
    case 1: s = k;  d = kb;  n4 = 4194304; break;
    case 2: s = v;  d = vb;  n4 = 4194304; break;
    case 3: s = Wq; d = Wqb; n4 = 262144; break;
    case 4: s = Wk; d = Wkb; n4 = 262144; break;
    case 5: s = Wv; d = Wvb; n4 = 262144; break;
    default: s = Wo; d = Wob; n4 = 262144; break;
  }
  for (int i = blockIdx.x * 256 + threadIdx.x; i < n4; i += gridDim.x * 256) {
    float4 f = ((const float4*)s)[i];
    ushort4 o;
    o.x = f2bf(f.x); o.y = f2bf(f.y); o.z = f2bf(f.z); o.w = f2bf(f.w);
    ((ushort4*)d)[i] = o;
  }
}

// ---------------- k2/k5: bf16 GEMM, C = A @ B^T + bias ----------------
// A: M x 1024 bf16 row-major, Bw: 1024 x 1024 bf16 row-major (torch Linear weight)
// MODE 0: relu, permuted bf16 store (B,H,L,64); MODE 1: same, no relu; MODE 2: fp32 plain
template <int MODE>
__global__ __launch_bounds__(256, 2) void gemm_bt(
    const unsigned short* __restrict__ A, const unsigned short* __restrict__ Bw,
    const float* __restrict__ bias, void* __restrict__ out) {
  constexpr int K = 1024;
  __shared__ unsigned short As[128 * 32];
  __shared__ unsigned short Bs[128 * 32];
  const int tid = threadIdx.x;
  const int wave = tid >> 6, lane = tid & 63;
  const int fr = lane & 15, fq = lane >> 4;
  const int wr = wave >> 1, wc = wave & 1;
  const int m0 = blockIdx.y * 128, n0 = blockIdx.x * 128;
  f32x4 acc[4][4] = {};
  const int srow = tid >> 2, scol = (tid & 3) << 3;
  const unsigned short* aS = A + (size_t)(m0 + srow) * K + scol;
  const unsigned short* bS = Bw + (size_t)(n0 + srow) * K + scol;
  for (int k0 = 0; k0 < K; k0 += 32) {
    __syncthreads();
    GLD16(aS + k0, As + (wave << 9));
    GLD16(aS + (size_t)64 * K + k0, As + 2048 + (wave << 9));
    GLD16(bS + k0, Bs + (wave << 9));
    GLD16(bS + (size_t)64 * K + k0, Bs + 2048 + (wave << 9));
    __syncthreads();
    bf16x8 av[4], bv[4];
#pragma unroll
    for (int m = 0; m < 4; ++m)
      av[m] = *(const bf16x8*)&As[(wr * 64 + m * 16 + fr) * 32 + fq * 8];
#pragma unroll
    for (int n = 0; n < 4; ++n)
      bv[n] = *(const bf16x8*)&Bs[(wc * 64 + n * 16 + fr) * 32 + fq * 8];
#pragma unroll
    for (int m = 0; m < 4; ++m)
#pragma unroll
      for (int n = 0; n < 4; ++n)
        acc[m][n] = __builtin_amdgcn_mfma_f32_16x16x32_bf16(av[m], bv[n], acc[m][n], 0, 0, 0);
  }
  const int rowb = m0 + wr * 64 + fq * 4;
  const int colb = n0 + wc * 64 + fr;
#pragma unroll
  for (int n = 0; n < 4; ++n) {
    const int col = colb + n * 16;
    const float bb = bias[col];
#pragma unroll
    for (int m = 0; m < 4; ++m) {
#pragma unroll
      for (int r = 0; r < 4; ++r) {
        const int i = rowb + m * 16 + r;
        float val = acc[m][n][r] + bb;
        if constexpr (MODE == 0) val = fmaxf(val, 0.0f);
        if constexpr (MODE == 2) {
          ((float*)out)[(size_t)i * 1024 + col] = val;
        } else {
          const int b = i >> 12, l = i & 4095, h = col >> 6, dd = col & 63;
          ((unsigned short*)out)[((size_t)((b << 4) + h) * 4096 + l) * 64 + dd] = f2bf(val);
        }
      }
    }
  }
}

// ---------------- k3: kv^T and ksum partial accumulation (VALU) ----------------
// grid 256 = (bh=64) x (lsplit=4); kv_part[bhls][d=64][c=128], ksum_part[bhls][c=128]
__global__ __launch_bounds__(256) void kv_accum(
    const unsigned short* __restrict__ Kh, const unsigned short* __restrict__ Vh,
    float* __restrict__ kv_part, float* __restrict__ ksum_part) {
  __shared__ unsigned short Ks[64 * 64];
  __shared__ unsigned short Vs[64 * 64];
  __shared__ float sn[64], cn[64];
  const int tid = threadIdx.x, wave = tid >> 6;
  const int bh = blockIdx.x >> 2, ls = blockIdx.x & 3;
  const int tc = tid >> 4, td = tid & 15;   // tc: c-block of 8 (0..15), td: d-block of 4
  const int khalf = tc & 7;
  float acc[8][4] = {};
  float ksa[8] = {};
  const size_t base = (size_t)bh * 4096 * 64;
  for (int t0 = 0; t0 < 1024; t0 += 64) {
    const int lg0 = ls * 1024 + t0;
    __syncthreads();
#pragma unroll
    for (int j = 0; j < 2; ++j) {
      const int n_ = j * 256 + tid;
      const size_t roff = base + (size_t)(lg0 + (n_ >> 3)) * 64 + (size_t)(n_ & 7) * 8;
      GLD16(Kh + roff, Ks + j * 2048 + (wave << 9));
      GLD16(Vh + roff, Vs + j * 2048 + (wave << 9));
    }
    if (tid < 64) {
      float sv, cv;
      __sincosf(PI_F * (float)(lg0 + tid + 1) * (1.0f / 8192.0f), &sv, &cv);
      sn[tid] = sv; cn[tid] = cv;
    }
    __syncthreads();
#pragma unroll 2
    for (int l = 0; l < 64; ++l) {
      const float sc = (tc < 8) ? sn[l] : cn[l];
      const uint4 kw = *(const uint4*)&Ks[l * 64 + khalf * 8];
      const uint2 vw = *(const uint2*)&Vs[l * 64 + td * 4];
      float kf[8], vf[4];
      kf[0] = __builtin_bit_cast(float, kw.x << 16) * sc;
      kf[1] = __builtin_bit_cast(float, kw.x & 0xffff0000u) * sc;
      kf[2] = __builtin_bit_cast(float, kw.y << 16) * sc;
      kf[3] = __builtin_bit_cast(float, kw.y & 0xffff0000u) * sc;
      kf[4] = __builtin_bit_cast(float, kw.z << 16) * sc;
      kf[5] = __builtin_bit_cast(float, kw.z & 0xffff0000u) * sc;
      kf[6] = __builtin_bit_cast(float, kw.w << 16) * sc;
      kf[7] = __builtin_bit_cast(float, kw.w & 0xffff0000u) * sc;
      vf[0] = __builtin_bit_cast(float, vw.x << 16);
      vf[1] = __builtin_bit_cast(float, vw.x & 0xffff0000u);
      vf[2] = __builtin_bit_cast(float, vw.y << 16);
      vf[3] = __builtin_bit_cast(float, vw.y & 0xffff0000u);
#pragma unroll
      for (int ci = 0; ci < 8; ++ci) {
        ksa[ci] += kf[ci];
#pragma unroll
        for (int di = 0; di < 4; ++di) acc[ci][di] += kf[ci] * vf[di];
      }
    }
  }
  float* kp = kv_part + (size_t)blockIdx.x * (64 * 128);
#pragma unroll
  for (int di = 0; di < 4; ++di)
#pragma unroll
    for (int ci = 0; ci < 8; ++ci)
      kp[(td * 4 + di) * 128 + tc * 8 + ci] = acc[ci][di];
  if (td == 0) {
    float* ksp = ksum_part + (size_t)blockIdx.x * 128;
#pragma unroll
    for (int ci = 0; ci < 8; ++ci) ksp[tc * 8 + ci] = ksa[ci];
  }
}

// ---------------- k3b: reduce partials -> kv_ext bf16 [bh][80][128] ----------------
// rows 0..63: kv^T[d][c]; row 64: ksum[c]; rows 65..79: 0
__global__ __launch_bounds__(256) void kv_reduce(
    const float* __restrict__ kv_part, const float* __restrict__ ksum_part,
    unsigned short* __restrict__ kv_ext) {
  const int bh = blockIdx.x;
  for (int e = threadIdx.x; e < 80 * 128; e += 256) {
    const int row = e >> 7, c = e & 127;
    float v = 0.0f;
    if (row < 64) {
#pragma unroll
      for (int ls = 0; ls < 4; ++ls)
        v += kv_part[((size_t)(bh * 4 + ls) * 64 + row) * 128 + c];
    } else if (row == 64) {
#pragma unroll
      for (int ls = 0; ls < 4; ++ls)
        v += ksum_part[(size_t)(bh * 4 + ls) * 128 + c];
    }
    kv_ext[(size_t)bh * (80 * 128) + e] = f2bf(v);
  }
}

// ---------------- k4: attn = (q_ @ kv) / max(q_ . ksum, eps) ----------------
// grid (32 l-tiles, 64 bh); M=128 l, N=80 (64 d + denom col 64), K=128 c
__global__ __launch_bounds__(256) void attn_phase2(
    const unsigned short* __restrict__ Qh, const unsigned short* __restrict__ kve,
    unsigned short* __restrict__ attn) {
  __shared__ unsigned short Qs[128 * 128];  // chunk-XOR-swizzled, 16 chunks/row
  __shared__ unsigned short Ws[80 * 128];
  const int tid = threadIdx.x, wave = tid >> 6, lane = tid & 63;
  const int fr = lane & 15, fq = lane >> 4;
  const int l0 = blockIdx.x * 128;
  const int bh = blockIdx.y, b = bh >> 4, h = bh & 15;
  // kv stage via global_load_lds (linear dest) with pre-swizzled source chunks
#pragma unroll
  for (int j = 0; j < 5; ++j) {
    const int p = j * 256 + tid;
    const int r = p >> 4, scn = p & 15;
    const int cc = scn ^ (r & 7);
    GLD16(kve + ((size_t)bh * 80 + r) * 128 + cc * 8,
          Ws + ((size_t)(j * 256 + wave * 64)) * 8);
  }
  // Q stage: reg-staged, expand [qh*sin | qh*cos], swizzled ds_write
#pragma unroll
  for (int it = 0; it < 4; ++it) {
    const int qc = it * 256 + tid;  // 0..1023 source chunks (r: 0..127, dc: 0..7)
    const int r = qc >> 3, dc = qc & 7;
    const uint4 w = *(const uint4*)(Qh + ((size_t)bh * 4096 + l0 + r) * 64 + dc * 8);
    float sv, cv;
    __sincosf(PI_F * (float)(l0 + r + 1) * (1.0f / 8192.0f), &sv, &cv);
    uint4 osn, ocs;
    osn.x = scale_pair(w.x, sv); osn.y = scale_pair(w.y, sv);
    osn.z = scale_pair(w.z, sv); osn.w = scale_pair(w.w, sv);
    ocs.x = scale_pair(w.x, cv); ocs.y = scale_pair(w.y, cv);
    ocs.z = scale_pair(w.z, cv); ocs.w = scale_pair(w.w, cv);
    const int ps = r * 16 + (dc ^ (r & 7));
    *(uint4*)&Qs[ps * 8] = osn;
    *(uint4*)&Qs[(ps + 8) * 8] = ocs;
  }
  __syncthreads();
  f32x4 acc[2][5] = {};
#pragma unroll
  for (int kk = 0; kk < 4; ++kk) {
    const int cc = kk * 4 + fq;
    bf16x8 a[2], bb[5];
#pragma unroll
    for (int m = 0; m < 2; ++m) {
      const int r = wave * 32 + m * 16 + fr;
      a[m] = *(const bf16x8*)&Qs[(r * 16 + (cc ^ (r & 7))) * 8];
    }
#pragma unroll
    for (int n = 0; n < 5; ++n) {
      const int r = n * 16 + fr;
      bb[n] = *(const bf16x8*)&Ws[(r * 16 + (cc ^ (r & 7))) * 8];
    }
#pragma unroll
    for (int m = 0; m < 2; ++m)
#pragma unroll
      for (int n = 0; n < 5; ++n)
        acc[m][n] = __builtin_amdgcn_mfma_f32_16x16x32_bf16(a[m], bb[n], acc[m][n], 0, 0, 0);
  }
#pragma unroll
  for (int m = 0; m < 2; ++m) {
#pragma unroll
    for (int r = 0; r < 4; ++r) {
      const float den = __shfl(acc[m][4][r], lane & 48);
      const float z = 1.0f / fmaxf(den, 1e-6f);
      const int l = l0 + wave * 32 + m * 16 + fq * 4 + r;
      const size_t ro = ((size_t)b * 4096 + l) * 1024 + (size_t)h * 64;
#pragma unroll
      for (int n = 0; n < 4; ++n)
        attn[ro + n * 16 + fr] = f2bf(acc[m][n][r] * z);
    }
  }
}

// ---------------- launch ----------------
extern "C" void kernel_launch(void* const* d_in, const int* in_sizes, int n_in,
                              void* d_out, int out_size, void* d_ws, size_t ws_size,
                              hipStream_t stream) {
  (void)in_sizes; (void)n_in; (void)out_size; (void)ws_size;
  const float* q  = (const float*)d_in[0];
  const float* k  = (const float*)d_in[1];
  const float* v  = (const float*)d_in[2];
  const float* Wq = (const float*)d_in[3];
  const float* bq = (const float*)d_in[4];
  const float* Wk = (const float*)d_in[5];
  const float* bk = (const float*)d_in[6];
  const float* Wv = (const float*)d_in[7];
  const float* bvp = (const float*)d_in[8];
  const float* Wo = (const float*)d_in[9];
  const float* bo = (const float*)d_in[10];

  char* ws = (char*)d_ws;
  // qb/kb parked in d_out (67,108,864 bytes == exactly 2 x 33,554,432)
  unsigned short* qb = (unsigned short*)d_out;
  unsigned short* kb = qb + 16777216;
  unsigned short* vb  = (unsigned short*)(ws + 0);
  unsigned short* Wqb = (unsigned short*)(ws + 33554432);
  unsigned short* Wkb = (unsigned short*)(ws + 35651584);
  unsigned short* Wvb = (unsigned short*)(ws + 37748736);
  unsigned short* Wob = (unsigned short*)(ws + 39845888);
  unsigned short* Qh  = (unsigned short*)(ws + 41943040);   // (bh, l, 64) bf16
  unsigned short* Kh  = (unsigned short*)(ws + 75497472);   // (bh, l, 64) bf16
  unsigned short* Vh  = (unsigned short*)(ws + 109051904);  // (bh, l, 64) bf16
  unsigned short* attnb = Vh;                               // alias: Vh dead after k3
  float* kvp = (float*)(ws + 142606336);                    // [256][64][128]
  float* ksp = (float*)(ws + 150994944);                    // [256][128]
  unsigned short* kve = (unsigned short*)(ws + 151126016);  // [64][80][128] bf16

  convert_all<<<dim3(512, 7), 256, 0, stream>>>(q, k, v, Wq, Wk, Wv, Wo,
                                                qb, kb, vb, Wqb, Wkb, Wvb, Wob);
  gemm_bt<0><<<dim3(8, 128), 256, 0, stream>>>(qb, Wqb, bq, Qh);
  gemm_bt<0><<<dim3(8, 128), 256, 0, stream>>>(kb, Wkb, bk, Kh);
  gemm_bt<1><<<dim3(8, 128), 256, 0, stream>>>(vb, Wvb, bvp, Vh);
  kv_accum<<<256, 256, 0, stream>>>(Kh, Vh, kvp, ksp);
  kv_reduce<<<64, 256, 0, stream>>>(kvp, ksp, kve);
  attn_phase2<<<dim3(32, 64), 256, 0, stream>>>(Qh, kve, attnb);
  gemm_bt<2><<<dim3(8, 128), 256, 0, stream>>>(attnb, Wob, bo, (float*)d_out);
}

// Round 2
// 331.090 us; speedup vs baseline: 1.2194x; 1.2194x over previous
//
#include <hip/hip_runtime.h>

typedef __bf16 bf16x8 __attribute__((ext_vector_type(8)));
typedef float f32x4 __attribute__((ext_vector_type(4)));

#define PI_F 3.14159265358979323846f

__device__ __forceinline__ unsigned short f2bf(float f) {
  unsigned u = __builtin_bit_cast(unsigned, f);
  u += 0x7fffu + ((u >> 16) & 1u);
  return (unsigned short)(u >> 16);
}

__device__ __forceinline__ unsigned scale_pair(unsigned w, float f) {
  const float lo = __builtin_bit_cast(float, w << 16);
  const float hi = __builtin_bit_cast(float, w & 0xffff0000u);
  return (unsigned)f2bf(lo * f) | ((unsigned)f2bf(hi * f) << 16);
}

#define GLD16(gp, lp)                                          \
  __builtin_amdgcn_global_load_lds(                            \
      (const __attribute__((address_space(1))) void*)(gp),     \
      (__attribute__((address_space(3))) void*)(lp), 16, 0, 0)

// ---------------- k1: fp32 -> bf16 conversion ----------------
__global__ __launch_bounds__(256) void convert_all(
    const float* __restrict__ q, const float* __restrict__ k, const float* __restrict__ v,
    const float* __restrict__ Wq, const float* __restrict__ Wk,
    const float* __restrict__ Wv, const float* __restrict__ Wo,
    unsigned short* __restrict__ qb, unsigned short* __restrict__ kb,
    unsigned short* __restrict__ vb, unsigned short* __restrict__ Wqb,
    unsigned short* __restrict__ Wkb, unsigned short* __restrict__ Wvb,
    unsigned short* __restrict__ Wob) {
  const int region = blockIdx.y;
  const float* s; unsigned short* d; int n4;
  switch (region) {
    case 0: s = q;  d = qb;  n4 = 4194304; break;
    case 1: s = k;  d = kb;  n4 = 4194304; break;
    case 2: s = v;  d = vb;  n4 = 4194304; break;
    case 3: s = Wq; d = Wqb; n4 = 262144; break;
    case 4: s = Wk; d = Wkb; n4 = 262144; break;
    case 5: s = Wv; d = Wvb; n4 = 262144; break;
    default: s = Wo; d = Wob; n4 = 262144; break;
  }
  for (int i = blockIdx.x * 256 + threadIdx.x; i < n4; i += gridDim.x * 256) {
    float4 f = ((const float4*)s)[i];
    ushort4 o;
    o.x = f2bf(f.x); o.y = f2bf(f.y); o.z = f2bf(f.z); o.w = f2bf(f.w);
    ((ushort4*)d)[i] = o;
  }
}

// ---------------- k2/k5: bf16 GEMM, C = A @ B^T + bias ----------------
// MODE 0: relu, permuted bf16 store (B,H,L,64)           -- Q proj
// MODE 2: fp32 plain row-major                            -- output proj
// MODE 3: relu, sin/cos expanded transposed K_ext[bh][128][4096] bf16
// MODE 4: no relu, transposed Vt[bh][64][4096] bf16
template <int MODE>
__global__ __launch_bounds__(256, 2) void gemm_bt(
    const unsigned short* __restrict__ A, const unsigned short* __restrict__ Bw,
    const float* __restrict__ bias, void* __restrict__ out) {
  constexpr int K = 1024;
  __shared__ unsigned short As[128 * 32];
  __shared__ unsigned short Bs[128 * 32];
  const int tid = threadIdx.x;
  const int wave = tid >> 6, lane = tid & 63;
  const int fr = lane & 15, fq = lane >> 4;
  const int wr = wave >> 1, wc = wave & 1;
  const int m0 = blockIdx.y * 128, n0 = blockIdx.x * 128;
  f32x4 acc[4][4] = {};
  const int srow = tid >> 2, scol = (tid & 3) << 3;
  const unsigned short* aS = A + (size_t)(m0 + srow) * K + scol;
  const unsigned short* bS = Bw + (size_t)(n0 + srow) * K + scol;
  for (int k0 = 0; k0 < K; k0 += 32) {
    __syncthreads();
    GLD16(aS + k0, As + (wave << 9));
    GLD16(aS + (size_t)64 * K + k0, As + 2048 + (wave << 9));
    GLD16(bS + k0, Bs + (wave << 9));
    GLD16(bS + (size_t)64 * K + k0, Bs + 2048 + (wave << 9));
    __syncthreads();
    bf16x8 av[4], bv[4];
#pragma unroll
    for (int m = 0; m < 4; ++m)
      av[m] = *(const bf16x8*)&As[(wr * 64 + m * 16 + fr) * 32 + fq * 8];
#pragma unroll
    for (int n = 0; n < 4; ++n)
      bv[n] = *(const bf16x8*)&Bs[(wc * 64 + n * 16 + fr) * 32 + fq * 8];
#pragma unroll
    for (int m = 0; m < 4; ++m)
#pragma unroll
      for (int n = 0; n < 4; ++n)
        acc[m][n] = __builtin_amdgcn_mfma_f32_16x16x32_bf16(av[m], bv[n], acc[m][n], 0, 0, 0);
  }
  const int rowb = m0 + wr * 64 + fq * 4;
  const int colb = n0 + wc * 64 + fr;
  if constexpr (MODE == 3 || MODE == 4) {
    float bb4[4];
#pragma unroll
    for (int n = 0; n < 4; ++n) bb4[n] = bias[colb + n * 16];
#pragma unroll
    for (int m = 0; m < 4; ++m) {
#pragma unroll
      for (int r = 0; r < 4; ++r) {
        const int i = rowb + m * 16 + r;
        const int b = i >> 12, l = i & 4095;
        float sv, cv;
        if constexpr (MODE == 3)
          __sincosf(PI_F * (float)(l + 1) * (1.0f / 8192.0f), &sv, &cv);
#pragma unroll
        for (int n = 0; n < 4; ++n) {
          const int col = colb + n * 16;
          const int h = col >> 6, dd = col & 63;
          float val = acc[m][n][r] + bb4[n];
          if constexpr (MODE == 3) {
            val = fmaxf(val, 0.0f);
            unsigned short* Kx = (unsigned short*)out;
            const size_t kb_ = ((size_t)((b << 4) + h) * 128 + dd) * 4096 + l;
            Kx[kb_] = f2bf(val * sv);
            Kx[kb_ + (size_t)64 * 4096] = f2bf(val * cv);
          } else {
            ((unsigned short*)out)[((size_t)((b << 4) + h) * 64 + dd) * 4096 + l] = f2bf(val);
          }
        }
      }
    }
  } else {
#pragma unroll
    for (int n = 0; n < 4; ++n) {
      const int col = colb + n * 16;
      const float bb = bias[col];
#pragma unroll
      for (int m = 0; m < 4; ++m) {
#pragma unroll
        for (int r = 0; r < 4; ++r) {
          const int i = rowb + m * 16 + r;
          float val = acc[m][n][r] + bb;
          if constexpr (MODE == 0) val = fmaxf(val, 0.0f);
          if constexpr (MODE == 2) {
            ((float*)out)[(size_t)i * 1024 + col] = val;
          } else {
            const int b = i >> 12, l = i & 4095, h = col >> 6, dd = col & 63;
            ((unsigned short*)out)[((size_t)((b << 4) + h) * 4096 + l) * 64 + dd] = f2bf(val);
          }
        }
      }
    }
  }
}

// ---------------- k3: kv partial GEMM via MFMA ----------------
// Per (ls, bh): C[65][128] f32 partial over K-range 512.
// A = Vt rows (d, l-contig), rows 64 = implicit ones (ksum). B^T = K_ext rows (c, l-contig).
__global__ __launch_bounds__(256, 2) void kv_gemm(
    const unsigned short* __restrict__ Vt,   // [64][64][4096]
    const unsigned short* __restrict__ Kx,   // [64][128][4096]
    float* __restrict__ kvp) {               // [64*8][65][128]
  __shared__ unsigned short As[64 * 64];     // [d][l] chunk-XOR swizzled
  __shared__ unsigned short Bs[128 * 64];    // [c][l] chunk-XOR swizzled
  const int tid = threadIdx.x, wave = tid >> 6, lane = tid & 63;
  const int fr = lane & 15, fq = lane >> 4;
  const int ls = blockIdx.x, bh = blockIdx.y;
  const size_t vbase = (size_t)bh * 64 * 4096;
  const size_t kbase = (size_t)bh * 128 * 4096;
  f32x4 acc[5][2] = {};
  bf16x8 ones;
#pragma unroll
  for (int j = 0; j < 8; ++j) ones[j] = (__bf16)1.0f;
  for (int t = 0; t < 8; ++t) {
    const int l0 = ls * 512 + t * 64;
    __syncthreads();
    // A: 512 chunks of 16B, pre-swizzled source
#pragma unroll
    for (int j = 0; j < 2; ++j) {
      const int p = j * 256 + tid;
      const int row = p >> 3, cc = (p & 7) ^ (row & 7);
      GLD16(Vt + vbase + (size_t)row * 4096 + l0 + cc * 8,
            As + ((j << 8) + (wave << 6)) * 8);
    }
    // B: 1024 chunks
#pragma unroll
    for (int j = 0; j < 4; ++j) {
      const int p = j * 256 + tid;
      const int row = p >> 3, cc = (p & 7) ^ (row & 7);
      GLD16(Kx + kbase + (size_t)row * 4096 + l0 + cc * 8,
            Bs + ((j << 8) + (wave << 6)) * 8);
    }
    __syncthreads();
#pragma unroll
    for (int kk = 0; kk < 2; ++kk) {
      const int ch = kk * 4 + fq;
      bf16x8 a[4], b[2];
#pragma unroll
      for (int m = 0; m < 4; ++m) {
        const int r = m * 16 + fr;
        a[m] = *(const bf16x8*)&As[(r * 8 + (ch ^ (r & 7))) * 8];
      }
#pragma unroll
      for (int n = 0; n < 2; ++n) {
        const int r = wave * 32 + n * 16 + fr;
        b[n] = *(const bf16x8*)&Bs[(r * 8 + (ch ^ (r & 7))) * 8];
      }
#pragma unroll
      for (int m = 0; m < 4; ++m)
#pragma unroll
        for (int n = 0; n < 2; ++n)
          acc[m][n] = __builtin_amdgcn_mfma_f32_16x16x32_bf16(a[m], b[n], acc[m][n], 0, 0, 0);
#pragma unroll
      for (int n = 0; n < 2; ++n)
        acc[4][n] = __builtin_amdgcn_mfma_f32_16x16x32_bf16(ones, b[n], acc[4][n], 0, 0, 0);
    }
  }
  float* outp = kvp + ((size_t)bh * 8 + ls) * (65 * 128);
  const int colb = wave * 32 + fr;
#pragma unroll
  for (int n = 0; n < 2; ++n) {
    const int col = colb + n * 16;
#pragma unroll
    for (int m = 0; m < 4; ++m)
#pragma unroll
      for (int r = 0; r < 4; ++r)
        outp[(m * 16 + fq * 4 + r) * 128 + col] = acc[m][n][r];
    if (fq == 0) outp[64 * 128 + col] = acc[4][n][0];
  }
}

// ---------------- k3b: reduce partials -> kv_ext bf16 [bh][80][128] ----------------
__global__ __launch_bounds__(256) void kv_reduce(
    const float* __restrict__ kvp, unsigned short* __restrict__ kv_ext) {
  const int bh = blockIdx.x;
  for (int e = threadIdx.x; e < 80 * 128; e += 256) {
    const int row = e >> 7, c = e & 127;
    float v = 0.0f;
    if (row < 65) {
#pragma unroll
      for (int ls = 0; ls < 8; ++ls)
        v += kvp[((size_t)bh * 8 + ls) * (65 * 128) + row * 128 + c];
    }
    kv_ext[(size_t)bh * (80 * 128) + e] = f2bf(v);
  }
}

// ---------------- k4: attn = (q_ @ kv) / max(q_ . ksum, eps) ----------------
__global__ __launch_bounds__(256) void attn_phase2(
    const unsigned short* __restrict__ Qh, const unsigned short* __restrict__ kve,
    unsigned short* __restrict__ attn) {
  __shared__ unsigned short Qs[128 * 128];
  __shared__ unsigned short Ws[80 * 128];
  const int tid = threadIdx.x, wave = tid >> 6, lane = tid & 63;
  const int fr = lane & 15, fq = lane >> 4;
  const int l0 = blockIdx.x * 128;
  const int bh = blockIdx.y, b = bh >> 4, h = bh & 15;
#pragma unroll
  for (int j = 0; j < 5; ++j) {
    const int p = j * 256 + tid;
    const int r = p >> 4, scn = p & 15;
    const int cc = scn ^ (r & 7);
    GLD16(kve + ((size_t)bh * 80 + r) * 128 + cc * 8,
          Ws + ((size_t)(j * 256 + wave * 64)) * 8);
  }
#pragma unroll
  for (int it = 0; it < 4; ++it) {
    const int qc = it * 256 + tid;
    const int r = qc >> 3, dc = qc & 7;
    const uint4 w = *(const uint4*)(Qh + ((size_t)bh * 4096 + l0 + r) * 64 + dc * 8);
    float sv, cv;
    __sincosf(PI_F * (float)(l0 + r + 1) * (1.0f / 8192.0f), &sv, &cv);
    uint4 osn, ocs;
    osn.x = scale_pair(w.x, sv); osn.y = scale_pair(w.y, sv);
    osn.z = scale_pair(w.z, sv); osn.w = scale_pair(w.w, sv);
    ocs.x = scale_pair(w.x, cv); ocs.y = scale_pair(w.y, cv);
    ocs.z = scale_pair(w.z, cv); ocs.w = scale_pair(w.w, cv);
    const int ps = r * 16 + (dc ^ (r & 7));
    *(uint4*)&Qs[ps * 8] = osn;
    *(uint4*)&Qs[(ps + 8) * 8] = ocs;
  }
  __syncthreads();
  f32x4 acc[2][5] = {};
#pragma unroll
  for (int kk = 0; kk < 4; ++kk) {
    const int cc = kk * 4 + fq;
    bf16x8 a[2], bb[5];
#pragma unroll
    for (int m = 0; m < 2; ++m) {
      const int r = wave * 32 + m * 16 + fr;
      a[m] = *(const bf16x8*)&Qs[(r * 16 + (cc ^ (r & 7))) * 8];
    }
#pragma unroll
    for (int n = 0; n < 5; ++n) {
      const int r = n * 16 + fr;
      bb[n] = *(const bf16x8*)&Ws[(r * 16 + (cc ^ (r & 7))) * 8];
    }
#pragma unroll
    for (int m = 0; m < 2; ++m)
#pragma unroll
      for (int n = 0; n < 5; ++n)
        acc[m][n] = __builtin_amdgcn_mfma_f32_16x16x32_bf16(a[m], bb[n], acc[m][n], 0, 0, 0);
  }
#pragma unroll
  for (int m = 0; m < 2; ++m) {
#pragma unroll
    for (int r = 0; r < 4; ++r) {
      const float den = __shfl(acc[m][4][r], lane & 48);
      const float z = 1.0f / fmaxf(den, 1e-6f);
      const int l = l0 + wave * 32 + m * 16 + fq * 4 + r;
      const size_t ro = ((size_t)b * 4096 + l) * 1024 + (size_t)h * 64;
#pragma unroll
      for (int n = 0; n < 4; ++n)
        attn[ro + n * 16 + fr] = f2bf(acc[m][n][r] * z);
    }
  }
}

// ---------------- launch ----------------
extern "C" void kernel_launch(void* const* d_in, const int* in_sizes, int n_in,
                              void* d_out, int out_size, void* d_ws, size_t ws_size,
                              hipStream_t stream) {
  (void)in_sizes; (void)n_in; (void)out_size; (void)ws_size;
  const float* q  = (const float*)d_in[0];
  const float* k  = (const float*)d_in[1];
  const float* v  = (const float*)d_in[2];
  const float* Wq = (const float*)d_in[3];
  const float* bq = (const float*)d_in[4];
  const float* Wk = (const float*)d_in[5];
  const float* bk = (const float*)d_in[6];
  const float* Wv = (const float*)d_in[7];
  const float* bvp = (const float*)d_in[8];
  const float* Wo = (const float*)d_in[9];
  const float* bo = (const float*)d_in[10];

  char* ws = (char*)d_ws;
  // ws layout (high-water 142.6 MB):
  unsigned short* qb  = (unsigned short*)(ws + 0);          // 32 MB (dead after Q-proj)
  unsigned short* kb  = (unsigned short*)(ws + 33554432);   // 32 MB (dead after K-proj)
  unsigned short* vb  = (unsigned short*)(ws + 67108864);   // 32 MB (dead after V-proj)
  unsigned short* Wqb = (unsigned short*)(ws + 100663296);
  unsigned short* Wkb = (unsigned short*)(ws + 102760448);
  unsigned short* Wvb = (unsigned short*)(ws + 104857600);
  unsigned short* Wob = (unsigned short*)(ws + 106954752);
  unsigned short* Qh  = (unsigned short*)(ws + 109051904);  // 32 MB (bh, l, 64)
  unsigned short* Vt  = qb;                                 // alias: [bh][64][4096]
  float* kvp          = (float*)kb;                         // alias: [512][65][128] f32 (17 MB)
  unsigned short* kve = (unsigned short*)(ws + 33554432 + 17039360);  // [64][80][128] bf16
  unsigned short* attnb = vb;                               // alias: [B,L,1024] bf16
  unsigned short* Kx  = (unsigned short*)d_out;             // K_ext [bh][128][4096] = 64 MB

  convert_all<<<dim3(512, 7), 256, 0, stream>>>(q, k, v, Wq, Wk, Wv, Wo,
                                                qb, kb, vb, Wqb, Wkb, Wvb, Wob);
  gemm_bt<0><<<dim3(8, 128), 256, 0, stream>>>(qb, Wqb, bq, Qh);
  gemm_bt<3><<<dim3(8, 128), 256, 0, stream>>>(kb, Wkb, bk, Kx);
  gemm_bt<4><<<dim3(8, 128), 256, 0, stream>>>(vb, Wvb, bvp, Vt);
  kv_gemm<<<dim3(8, 64), 256, 0, stream>>>(Vt, Kx, kvp);
  kv_reduce<<<64, 256, 0, stream>>>(kvp, kve);
  attn_phase2<<<dim3(32, 64), 256, 0, stream>>>(Qh, kve, attnb);
  gemm_bt<2><<<dim3(8, 128), 256, 0, stream>>>(attnb, Wob, bo, (float*)d_out);
}

// Round 3
// 310.576 us; speedup vs baseline: 1.2999x; 1.0661x over previous
//
#include <hip/hip_runtime.h>

typedef __bf16 bf16x8 __attribute__((ext_vector_type(8)));
typedef float f32x4 __attribute__((ext_vector_type(4)));

#define PI_F 3.14159265358979323846f

__device__ __forceinline__ unsigned short f2bf(float f) {
  unsigned u = __builtin_bit_cast(unsigned, f);
  u += 0x7fffu + ((u >> 16) & 1u);
  return (unsigned short)(u >> 16);
}

__device__ __forceinline__ unsigned scale_pair(unsigned w, float f) {
  const float lo = __builtin_bit_cast(float, w << 16);
  const float hi = __builtin_bit_cast(float, w & 0xffff0000u);
  return (unsigned)f2bf(lo * f) | ((unsigned)f2bf(hi * f) << 16);
}

#define GLD16(gp, lp)                                          \
  __builtin_amdgcn_global_load_lds(                            \
      (const __attribute__((address_space(1))) void*)(gp),     \
      (__attribute__((address_space(3))) void*)(lp), 16, 0, 0)

__device__ __forceinline__ ushort4 cvt4(float4 f) {
  ushort4 o;
  o.x = f2bf(f.x); o.y = f2bf(f.y); o.z = f2bf(f.z); o.w = f2bf(f.w);
  return o;
}

// ---------------- k1: fp32 -> bf16 conversion (4x MLP) ----------------
__global__ __launch_bounds__(256) void convert_all(
    const float* __restrict__ q, const float* __restrict__ k, const float* __restrict__ v,
    const float* __restrict__ Wq, const float* __restrict__ Wk,
    const float* __restrict__ Wv, const float* __restrict__ Wo,
    unsigned short* __restrict__ qb, unsigned short* __restrict__ kb,
    unsigned short* __restrict__ vb, unsigned short* __restrict__ Wqb,
    unsigned short* __restrict__ Wkb, unsigned short* __restrict__ Wvb,
    unsigned short* __restrict__ Wob) {
  const int region = blockIdx.y;
  const float* s; unsigned short* d; int n4;
  switch (region) {
    case 0: s = q;  d = qb;  n4 = 4194304; break;
    case 1: s = k;  d = kb;  n4 = 4194304; break;
    case 2: s = v;  d = vb;  n4 = 4194304; break;
    case 3: s = Wq; d = Wqb; n4 = 262144; break;
    case 4: s = Wk; d = Wkb; n4 = 262144; break;
    case 5: s = Wv; d = Wvb; n4 = 262144; break;
    default: s = Wo; d = Wob; n4 = 262144; break;
  }
  const float4* s4 = (const float4*)s;
  ushort4* d4 = (ushort4*)d;
  // n4 is always a multiple of 1024, so base < n4 implies base+768 < n4.
  for (int base = blockIdx.x * 1024 + threadIdx.x; base < n4; base += gridDim.x * 1024) {
    float4 f0 = s4[base];
    float4 f1 = s4[base + 256];
    float4 f2 = s4[base + 512];
    float4 f3 = s4[base + 768];
    d4[base] = cvt4(f0);
    d4[base + 256] = cvt4(f1);
    d4[base + 512] = cvt4(f2);
    d4[base + 768] = cvt4(f3);
  }
}

// ---------------- 256x256 8-phase bf16 GEMM, C = A @ B^T + bias ----------------
// A: 16384 x 1024 bf16 row-major; Bw: 1024 x 1024 bf16 row-major.
// MODE 0: relu, permuted bf16 store (B,H,L,64)              -- Q proj
// MODE 2: fp32 plain row-major                               -- output proj
// MODE 3: relu, sin/cos expanded transposed K_ext[bh][128][4096] bf16
// MODE 4: no relu, transposed Vt[bh][64][4096] bf16
// Geometry: BM=BN=256, BK=64, 8 waves (2Mx4N), per-wave out 128x64,
// LDS 128 KiB = 2buf x {A,B} x 2half x [128][64] bf16, swizzle byte^=(row&7)<<4.
template <int MODE>
__global__ __launch_bounds__(512, 2) void gemm256(
    const unsigned short* __restrict__ A, const unsigned short* __restrict__ Bw,
    const float* __restrict__ bias, void* __restrict__ out) {
  constexpr int K = 1024, NKT = 16;
  __shared__ unsigned short S[65536];  // [buf:32768][op:16384][half:8192] elems
  const int tid = threadIdx.x;
  const int wave = tid >> 6, lane = tid & 63;
  const int fr = lane & 15, fq = lane >> 4;
  const int wr = wave >> 2, wc = wave & 3;
  // bijective XCD swizzle (gridDim.x == 256, % 8 == 0)
  const int cpx = gridDim.x >> 3;
  const int wg = (blockIdx.x & 7) * cpx + (blockIdx.x >> 3);
  const int mt = wg >> 2, ntile = wg & 3;
  const int m0 = mt * 256, n0 = ntile * 256;

  // stage source addressing: thread t covers 16B at linear pos t*16 of an 8KB
  // segment; source column pre-swizzled so swizzled ds_reads see linear data.
  const int srow = tid >> 3;                                   // 0..63
  const int scolE = (((tid & 7) << 4) ^ ((srow & 7) << 4)) >> 1;  // elems
  const unsigned short* aSrc = A + (size_t)(m0 + srow) * K + scolE;
  const unsigned short* bSrc = Bw + (size_t)(n0 + srow) * K + scolE;

#define STAGE(kt_, buf_) do {                                                   \
    const int kc_ = (kt_) * 64;                                                 \
    GLD16(aSrc + kc_,                    S + (buf_) * 32768 +     0 + wave * 512); \
    GLD16(aSrc + (size_t)65536 + kc_,    S + (buf_) * 32768 +  4096 + wave * 512); \
    GLD16(aSrc + (size_t)131072 + kc_,   S + (buf_) * 32768 +  8192 + wave * 512); \
    GLD16(aSrc + (size_t)196608 + kc_,   S + (buf_) * 32768 + 12288 + wave * 512); \
    GLD16(bSrc + kc_,                    S + (buf_) * 32768 + 16384 + wave * 512); \
    GLD16(bSrc + (size_t)65536 + kc_,    S + (buf_) * 32768 + 20480 + wave * 512); \
    GLD16(bSrc + (size_t)131072 + kc_,   S + (buf_) * 32768 + 24576 + wave * 512); \
    GLD16(bSrc + (size_t)196608 + kc_,   S + (buf_) * 32768 + 28672 + wave * 512); \
  } while (0)

  // ds_read lane constants: col byte = (ks*64 + fq*16) ^ ((row&7)<<4); row&7 == fr&7
  const int xorv = (fr & 7) << 4;
  const unsigned cbE0 = (unsigned)(((fq * 16) ^ xorv) >> 1);
  const unsigned cbE1 = (unsigned)(((64 + fq * 16) ^ xorv) >> 1);

  f32x4 acc[8][4] = {};
  STAGE(0, 0);
  asm volatile("s_waitcnt vmcnt(0)" ::: "memory");
  __syncthreads();

  for (int kt = 0; kt < NKT; ++kt) {
    const int buf = kt & 1;
    const unsigned aB = (unsigned)(buf * 32768 + wr * 8192 + fr * 64);
    const unsigned bB = (unsigned)(buf * 32768 + 16384 + (wc >> 1) * 8192 +
                                   ((wc & 1) * 64 + fr) * 64);
#pragma unroll
    for (int ph = 0; ph < 4; ++ph) {
      const int mh = ph >> 1, nh = ph & 1;
      bf16x8 af[4][2], bfr[2][2];
#pragma unroll
      for (int mm = 0; mm < 4; ++mm) {
        const unsigned r = aB + (unsigned)((mh * 4 + mm) * 1024);
        af[mm][0] = *(const bf16x8*)&S[r + cbE0];
        af[mm][1] = *(const bf16x8*)&S[r + cbE1];
      }
#pragma unroll
      for (int nn = 0; nn < 2; ++nn) {
        const unsigned r = bB + (unsigned)((nh * 2 + nn) * 1024);
        bfr[nn][0] = *(const bf16x8*)&S[r + cbE0];
        bfr[nn][1] = *(const bf16x8*)&S[r + cbE1];
      }
      if (ph == 0 && kt + 1 < NKT) STAGE(kt + 1, buf ^ 1);
      __builtin_amdgcn_s_barrier();
      __builtin_amdgcn_s_setprio(1);
#pragma unroll
      for (int mm = 0; mm < 4; ++mm)
#pragma unroll
        for (int nn = 0; nn < 2; ++nn) {
          acc[mh * 4 + mm][nh * 2 + nn] = __builtin_amdgcn_mfma_f32_16x16x32_bf16(
              af[mm][0], bfr[nn][0], acc[mh * 4 + mm][nh * 2 + nn], 0, 0, 0);
          acc[mh * 4 + mm][nh * 2 + nn] = __builtin_amdgcn_mfma_f32_16x16x32_bf16(
              af[mm][1], bfr[nn][1], acc[mh * 4 + mm][nh * 2 + nn], 0, 0, 0);
        }
      __builtin_amdgcn_s_setprio(0);
      if (ph == 3) asm volatile("s_waitcnt vmcnt(0)" ::: "memory");
      __builtin_amdgcn_s_barrier();
    }
  }
#undef STAGE

  const int rowb = m0 + wr * 128 + fq * 4;
  const int colb = n0 + wc * 64 + fr;
  if constexpr (MODE == 3 || MODE == 4) {
    float bb4[4];
#pragma unroll
    for (int nq = 0; nq < 4; ++nq) bb4[nq] = bias[colb + nq * 16];
#pragma unroll
    for (int mq = 0; mq < 8; ++mq) {
#pragma unroll
      for (int rr = 0; rr < 4; ++rr) {
        const int i = rowb + mq * 16 + rr;
        const int b = i >> 12, l = i & 4095;
        float sv, cv;
        if constexpr (MODE == 3)
          __sincosf(PI_F * (float)(l + 1) * (1.0f / 8192.0f), &sv, &cv);
#pragma unroll
        for (int nq = 0; nq < 4; ++nq) {
          const int col = colb + nq * 16;
          const int h = col >> 6, dd = col & 63;
          float val = acc[mq][nq][rr] + bb4[nq];
          if constexpr (MODE == 3) {
            val = fmaxf(val, 0.0f);
            unsigned short* Kx = (unsigned short*)out;
            const size_t kb_ = ((size_t)((b << 4) + h) * 128 + dd) * 4096 + l;
            Kx[kb_] = f2bf(val * sv);
            Kx[kb_ + (size_t)64 * 4096] = f2bf(val * cv);
          } else {
            ((unsigned short*)out)[((size_t)((b << 4) + h) * 64 + dd) * 4096 + l] = f2bf(val);
          }
        }
      }
    }
  } else {
#pragma unroll
    for (int nq = 0; nq < 4; ++nq) {
      const int col = colb + nq * 16;
      const float bb = bias[col];
#pragma unroll
      for (int mq = 0; mq < 8; ++mq) {
#pragma unroll
        for (int rr = 0; rr < 4; ++rr) {
          const int i = rowb + mq * 16 + rr;
          float val = acc[mq][nq][rr] + bb;
          if constexpr (MODE == 0) val = fmaxf(val, 0.0f);
          if constexpr (MODE == 2) {
            ((float*)out)[(size_t)i * 1024 + col] = val;
          } else {
            const int b = i >> 12, l = i & 4095, h = col >> 6, dd = col & 63;
            ((unsigned short*)out)[((size_t)((b << 4) + h) * 4096 + l) * 64 + dd] = f2bf(val);
          }
        }
      }
    }
  }
}

// ---------------- k3: kv partial GEMM via MFMA ----------------
__global__ __launch_bounds__(256, 2) void kv_gemm(
    const unsigned short* __restrict__ Vt,   // [64][64][4096]
    const unsigned short* __restrict__ Kx,   // [64][128][4096]
    float* __restrict__ kvp) {               // [64*8][65][128]
  __shared__ unsigned short As[64 * 64];
  __shared__ unsigned short Bs[128 * 64];
  const int tid = threadIdx.x, wave = tid >> 6, lane = tid & 63;
  const int fr = lane & 15, fq = lane >> 4;
  const int ls = blockIdx.x, bh = blockIdx.y;
  const size_t vbase = (size_t)bh * 64 * 4096;
  const size_t kbase = (size_t)bh * 128 * 4096;
  f32x4 acc[5][2] = {};
  bf16x8 ones;
#pragma unroll
  for (int j = 0; j < 8; ++j) ones[j] = (__bf16)1.0f;
  for (int t = 0; t < 8; ++t) {
    const int l0 = ls * 512 + t * 64;
    __syncthreads();
#pragma unroll
    for (int j = 0; j < 2; ++j) {
      const int p = j * 256 + tid;
      const int row = p >> 3, cc = (p & 7) ^ (row & 7);
      GLD16(Vt + vbase + (size_t)row * 4096 + l0 + cc * 8,
            As + ((j << 8) + (wave << 6)) * 8);
    }
#pragma unroll
    for (int j = 0; j < 4; ++j) {
      const int p = j * 256 + tid;
      const int row = p >> 3, cc = (p & 7) ^ (row & 7);
      GLD16(Kx + kbase + (size_t)row * 4096 + l0 + cc * 8,
            Bs + ((j << 8) + (wave << 6)) * 8);
    }
    __syncthreads();
#pragma unroll
    for (int kk = 0; kk < 2; ++kk) {
      const int ch = kk * 4 + fq;
      bf16x8 a[4], b[2];
#pragma unroll
      for (int m = 0; m < 4; ++m) {
        const int r = m * 16 + fr;
        a[m] = *(const bf16x8*)&As[(r * 8 + (ch ^ (r & 7))) * 8];
      }
#pragma unroll
      for (int n = 0; n < 2; ++n) {
        const int r = wave * 32 + n * 16 + fr;
        b[n] = *(const bf16x8*)&Bs[(r * 8 + (ch ^ (r & 7))) * 8];
      }
#pragma unroll
      for (int m = 0; m < 4; ++m)
#pragma unroll
        for (int n = 0; n < 2; ++n)
          acc[m][n] = __builtin_amdgcn_mfma_f32_16x16x32_bf16(a[m], b[n], acc[m][n], 0, 0, 0);
#pragma unroll
      for (int n = 0; n < 2; ++n)
        acc[4][n] = __builtin_amdgcn_mfma_f32_16x16x32_bf16(ones, b[n], acc[4][n], 0, 0, 0);
    }
  }
  float* outp = kvp + ((size_t)bh * 8 + ls) * (65 * 128);
  const int colb = wave * 32 + fr;
#pragma unroll
  for (int n = 0; n < 2; ++n) {
    const int col = colb + n * 16;
#pragma unroll
    for (int m = 0; m < 4; ++m)
#pragma unroll
      for (int r = 0; r < 4; ++r)
        outp[(m * 16 + fq * 4 + r) * 128 + col] = acc[m][n][r];
    if (fq == 0) outp[64 * 128 + col] = acc[4][n][0];
  }
}

// ---------------- k3b: reduce partials -> kv_ext bf16 [bh][80][128] ----------------
__global__ __launch_bounds__(256) void kv_reduce(
    const float* __restrict__ kvp, unsigned short* __restrict__ kv_ext) {
  const int bh = blockIdx.x;
  for (int e = threadIdx.x; e < 80 * 128; e += 256) {
    const int row = e >> 7, c = e & 127;
    float v = 0.0f;
    if (row < 65) {
#pragma unroll
      for (int ls = 0; ls < 8; ++ls)
        v += kvp[((size_t)bh * 8 + ls) * (65 * 128) + row * 128 + c];
    }
    kv_ext[(size_t)bh * (80 * 128) + e] = f2bf(v);
  }
}

// ---------------- k4: attn = (q_ @ kv) / max(q_ . ksum, eps) ----------------
__global__ __launch_bounds__(256) void attn_phase2(
    const unsigned short* __restrict__ Qh, const unsigned short* __restrict__ kve,
    unsigned short* __restrict__ attn) {
  __shared__ unsigned short Qs[128 * 128];
  __shared__ unsigned short Ws[80 * 128];
  const int tid = threadIdx.x, wave = tid >> 6, lane = tid & 63;
  const int fr = lane & 15, fq = lane >> 4;
  const int l0 = blockIdx.x * 128;
  const int bh = blockIdx.y, b = bh >> 4, h = bh & 15;
#pragma unroll
  for (int j = 0; j < 5; ++j) {
    const int p = j * 256 + tid;
    const int r = p >> 4, scn = p & 15;
    const int cc = scn ^ (r & 7);
    GLD16(kve + ((size_t)bh * 80 + r) * 128 + cc * 8,
          Ws + ((size_t)(j * 256 + wave * 64)) * 8);
  }
#pragma unroll
  for (int it = 0; it < 4; ++it) {
    const int qc = it * 256 + tid;
    const int r = qc >> 3, dc = qc & 7;
    const uint4 w = *(const uint4*)(Qh + ((size_t)bh * 4096 + l0 + r) * 64 + dc * 8);
    float sv, cv;
    __sincosf(PI_F * (float)(l0 + r + 1) * (1.0f / 8192.0f), &sv, &cv);
    uint4 osn, ocs;
    osn.x = scale_pair(w.x, sv); osn.y = scale_pair(w.y, sv);
    osn.z = scale_pair(w.z, sv); osn.w = scale_pair(w.w, sv);
    ocs.x = scale_pair(w.x, cv); ocs.y = scale_pair(w.y, cv);
    ocs.z = scale_pair(w.z, cv); ocs.w = scale_pair(w.w, cv);
    const int ps = r * 16 + (dc ^ (r & 7));
    *(uint4*)&Qs[ps * 8] = osn;
    *(uint4*)&Qs[(ps + 8) * 8] = ocs;
  }
  __syncthreads();
  f32x4 acc[2][5] = {};
#pragma unroll
  for (int kk = 0; kk < 4; ++kk) {
    const int cc = kk * 4 + fq;
    bf16x8 a[2], bb[5];
#pragma unroll
    for (int m = 0; m < 2; ++m) {
      const int r = wave * 32 + m * 16 + fr;
      a[m] = *(const bf16x8*)&Qs[(r * 16 + (cc ^ (r & 7))) * 8];
    }
#pragma unroll
    for (int n = 0; n < 5; ++n) {
      const int r = n * 16 + fr;
      bb[n] = *(const bf16x8*)&Ws[(r * 16 + (cc ^ (r & 7))) * 8];
    }
#pragma unroll
    for (int m = 0; m < 2; ++m)
#pragma unroll
      for (int n = 0; n < 5; ++n)
        acc[m][n] = __builtin_amdgcn_mfma_f32_16x16x32_bf16(a[m], bb[n], acc[m][n], 0, 0, 0);
  }
#pragma unroll
  for (int m = 0; m < 2; ++m) {
#pragma unroll
    for (int r = 0; r < 4; ++r) {
      const float den = __shfl(acc[m][4][r], lane & 48);
      const float z = 1.0f / fmaxf(den, 1e-6f);
      const int l = l0 + wave * 32 + m * 16 + fq * 4 + r;
      const size_t ro = ((size_t)b * 4096 + l) * 1024 + (size_t)h * 64;
#pragma unroll
      for (int n = 0; n < 4; ++n)
        attn[ro + n * 16 + fr] = f2bf(acc[m][n][r] * z);
    }
  }
}

// ---------------- launch ----------------
extern "C" void kernel_launch(void* const* d_in, const int* in_sizes, int n_in,
                              void* d_out, int out_size, void* d_ws, size_t ws_size,
                              hipStream_t stream) {
  (void)in_sizes; (void)n_in; (void)out_size; (void)ws_size;
  const float* q  = (const float*)d_in[0];
  const float* k  = (const float*)d_in[1];
  const float* v  = (const float*)d_in[2];
  const float* Wq = (const float*)d_in[3];
  const float* bq = (const float*)d_in[4];
  const float* Wk = (const float*)d_in[5];
  const float* bk = (const float*)d_in[6];
  const float* Wv = (const float*)d_in[7];
  const float* bvp = (const float*)d_in[8];
  const float* Wo = (const float*)d_in[9];
  const float* bo = (const float*)d_in[10];

  char* ws = (char*)d_ws;
  unsigned short* qb  = (unsigned short*)(ws + 0);          // 32 MB (dead after Q-proj)
  unsigned short* kb  = (unsigned short*)(ws + 33554432);   // 32 MB (dead after K-proj)
  unsigned short* vb  = (unsigned short*)(ws + 67108864);   // 32 MB (dead after V-proj)
  unsigned short* Wqb = (unsigned short*)(ws + 100663296);
  unsigned short* Wkb = (unsigned short*)(ws + 102760448);
  unsigned short* Wvb = (unsigned short*)(ws + 104857600);
  unsigned short* Wob = (unsigned short*)(ws + 106954752);
  unsigned short* Qh  = (unsigned short*)(ws + 109051904);  // 32 MB (bh, l, 64)
  unsigned short* Vt  = qb;                                 // alias: [bh][64][4096]
  float* kvp          = (float*)kb;                         // alias: [512][65][128] f32
  unsigned short* kve = (unsigned short*)(ws + 33554432 + 17039360);  // [64][80][128]
  unsigned short* attnb = vb;                               // alias: [B,L,1024] bf16
  unsigned short* Kx  = (unsigned short*)d_out;             // K_ext [bh][128][4096]

  convert_all<<<dim3(512, 7), 256, 0, stream>>>(q, k, v, Wq, Wk, Wv, Wo,
                                                qb, kb, vb, Wqb, Wkb, Wvb, Wob);
  gemm256<0><<<256, 512, 0, stream>>>(qb, Wqb, bq, Qh);
  gemm256<3><<<256, 512, 0, stream>>>(kb, Wkb, bk, Kx);
  gemm256<4><<<256, 512, 0, stream>>>(vb, Wvb, bvp, Vt);
  kv_gemm<<<dim3(8, 64), 256, 0, stream>>>(Vt, Kx, kvp);
  kv_reduce<<<64, 256, 0, stream>>>(kvp, kve);
  attn_phase2<<<dim3(32, 64), 256, 0, stream>>>(Qh, kve, attnb);
  gemm256<2><<<256, 512, 0, stream>>>(attnb, Wob, bo, (float*)d_out);
}

// Round 4
// 307.782 us; speedup vs baseline: 1.3117x; 1.0091x over previous
//
#include <hip/hip_runtime.h>

typedef __bf16 bf16x8 __attribute__((ext_vector_type(8)));
typedef float f32x4 __attribute__((ext_vector_type(4)));

#define PI_F 3.14159265358979323846f

__device__ __forceinline__ unsigned short f2bf(float f) {
  unsigned u = __builtin_bit_cast(unsigned, f);
  u += 0x7fffu + ((u >> 16) & 1u);
  return (unsigned short)(u >> 16);
}

__device__ __forceinline__ unsigned scale_pair(unsigned w, float f) {
  const float lo = __builtin_bit_cast(float, w << 16);
  const float hi = __builtin_bit_cast(float, w & 0xffff0000u);
  return (unsigned)f2bf(lo * f) | ((unsigned)f2bf(hi * f) << 16);
}

#define GLD16(gp, lp)                                          \
  __builtin_amdgcn_global_load_lds(                            \
      (const __attribute__((address_space(1))) void*)(gp),     \
      (__attribute__((address_space(3))) void*)(lp), 16, 0, 0)

struct AReg { float4 a0, a1, a2, a3, a4, a5, a6, a7; };

__device__ __forceinline__ uint4 cvtpk16(float4 x, float4 y) {
  unsigned c0, c1, c2, c3;
  asm("v_cvt_pk_bf16_f32 %0, %1, %2" : "=v"(c0) : "v"(x.x), "v"(x.y));
  asm("v_cvt_pk_bf16_f32 %0, %1, %2" : "=v"(c1) : "v"(x.z), "v"(x.w));
  asm("v_cvt_pk_bf16_f32 %0, %1, %2" : "=v"(c2) : "v"(y.x), "v"(y.y));
  asm("v_cvt_pk_bf16_f32 %0, %1, %2" : "=v"(c3) : "v"(y.z), "v"(y.w));
  uint4 u; u.x = c0; u.y = c1; u.z = c2; u.w = c3;
  return u;
}

// ---------------- k1: weight fp32 -> bf16 conversion (weights only) ----------------
__global__ __launch_bounds__(256) void convert_w(
    const float* __restrict__ Wq, const float* __restrict__ Wk,
    const float* __restrict__ Wv, const float* __restrict__ Wo,
    unsigned short* __restrict__ Wqb, unsigned short* __restrict__ Wkb,
    unsigned short* __restrict__ Wvb, unsigned short* __restrict__ Wob) {
  const int region = blockIdx.y;
  const float* s; unsigned short* d;
  switch (region) {
    case 0: s = Wq; d = Wqb; break;
    case 1: s = Wk; d = Wkb; break;
    case 2: s = Wv; d = Wvb; break;
    default: s = Wo; d = Wob; break;
  }
  const float4* s4 = (const float4*)s;
  ushort4* d4 = (ushort4*)d;
  const int n4 = 262144;
  for (int i = blockIdx.x * 256 + threadIdx.x; i < n4; i += gridDim.x * 256) {
    float4 f = s4[i];
    ushort4 o;
    o.x = f2bf(f.x); o.y = f2bf(f.y); o.z = f2bf(f.z); o.w = f2bf(f.w);
    d4[i] = o;
  }
}

// ---------------- 256x256 8-phase bf16 GEMM, C = A @ B^T + bias ----------------
// A: 16384 x 1024 row-major (fp32 if AF32, else bf16); Bw: 1024 x 1024 bf16.
// MODE 0: relu, permuted bf16 store (B,H,L,64)              -- Q proj
// MODE 2: fp32 plain row-major                               -- output proj
// MODE 3: relu, sin/cos expanded transposed K_ext[bh][128][4096] bf16
// MODE 4: no relu, transposed Vt[bh][64][4096] bf16
template <int MODE, bool AF32>
__global__ __launch_bounds__(512, 2) void gemm256(
    const void* __restrict__ Ain, const unsigned short* __restrict__ Bw,
    const float* __restrict__ bias, void* __restrict__ out) {
  constexpr int K = 1024, NKT = 16;
  __shared__ unsigned short S[65536];  // [buf:32768][A:16384|B:16384]
  const int tid = threadIdx.x;
  const int wave = tid >> 6, lane = tid & 63;
  const int fr = lane & 15, fq = lane >> 4;
  const int wr = wave >> 2, wc = wave & 3;
  const int cpx = gridDim.x >> 3;
  const int wg = (blockIdx.x & 7) * cpx + (blockIdx.x >> 3);
  const int mt = wg >> 2, ntile = wg & 3;
  const int m0 = mt * 256, n0 = ntile * 256;

  // staging thread mapping: srow = row-in-64-group, 16B chunk ac16
  const int srow = tid >> 3;
  const int ac16 = tid & 7;
  const int scolE = ((ac16 << 4) ^ ((srow & 7) << 4)) >> 1;  // pre-swizzled src col (elems)
  const unsigned short* bSrc = Bw + (size_t)(n0 + srow) * K + scolE;
  const unsigned short* aSrcB =
      AF32 ? (const unsigned short*)nullptr
           : ((const unsigned short*)Ain + (size_t)(m0 + srow) * K + scolE);
  const float* A32 = (const float*)Ain;
  const int awoff = (ac16 ^ (srow & 7)) << 3;  // swizzled dst chunk (elems)
  AReg R;

#define BSTAGE(kt_, buf_) do {                                                     \
    const int kc_ = (kt_) * 64;                                                    \
    GLD16(bSrc + kc_,                  S + (buf_) * 32768 + 16384 + wave * 512);   \
    GLD16(bSrc + (size_t)65536 + kc_,  S + (buf_) * 32768 + 20480 + wave * 512);   \
    GLD16(bSrc + (size_t)131072 + kc_, S + (buf_) * 32768 + 24576 + wave * 512);   \
    GLD16(bSrc + (size_t)196608 + kc_, S + (buf_) * 32768 + 28672 + wave * 512);   \
  } while (0)

#define ASTAGE(kt_, buf_) do {                                                     \
    const int kc_ = (kt_) * 64;                                                    \
    GLD16(aSrcB + kc_,                  S + (buf_) * 32768 +     0 + wave * 512);  \
    GLD16(aSrcB + (size_t)65536 + kc_,  S + (buf_) * 32768 +  4096 + wave * 512);  \
    GLD16(aSrcB + (size_t)131072 + kc_, S + (buf_) * 32768 +  8192 + wave * 512);  \
    GLD16(aSrcB + (size_t)196608 + kc_, S + (buf_) * 32768 + 12288 + wave * 512);  \
  } while (0)

#define ALOAD_ALL(kt_) do {                                                        \
    const int kc_ = (kt_) * 64;                                                    \
    const float4* p_;                                                              \
    p_ = (const float4*)(A32 + (size_t)(m0 + srow) * K + kc_) + ac16 * 2;          \
    R.a0 = p_[0]; R.a1 = p_[1];                                                    \
    p_ = (const float4*)(A32 + (size_t)(m0 + 64 + srow) * K + kc_) + ac16 * 2;     \
    R.a2 = p_[0]; R.a3 = p_[1];                                                    \
    p_ = (const float4*)(A32 + (size_t)(m0 + 128 + srow) * K + kc_) + ac16 * 2;    \
    R.a4 = p_[0]; R.a5 = p_[1];                                                    \
    p_ = (const float4*)(A32 + (size_t)(m0 + 192 + srow) * K + kc_) + ac16 * 2;    \
    R.a6 = p_[0]; R.a7 = p_[1];                                                    \
  } while (0)

#define AWRITE_ALL(buf_) do {                                                      \
    unsigned short* dst_ = &S[(buf_) * 32768 + srow * 64 + awoff];                 \
    *(uint4*)(dst_)         = cvtpk16(R.a0, R.a1);                                 \
    *(uint4*)(dst_ + 4096)  = cvtpk16(R.a2, R.a3);                                 \
    *(uint4*)(dst_ + 8192)  = cvtpk16(R.a4, R.a5);                                 \
    *(uint4*)(dst_ + 12288) = cvtpk16(R.a6, R.a7);                                 \
  } while (0)

  // ds_read lane constants
  const int xorv = (fr & 7) << 4;
  const unsigned cbE0 = (unsigned)(((fq * 16) ^ xorv) >> 1);
  const unsigned cbE1 = (unsigned)(((64 + fq * 16) ^ xorv) >> 1);

  f32x4 acc[8][4] = {};
  if constexpr (AF32) {
    ALOAD_ALL(0);
    BSTAGE(0, 0);
    AWRITE_ALL(0);
  } else {
    BSTAGE(0, 0);
    ASTAGE(0, 0);
  }
  asm volatile("s_waitcnt vmcnt(0) lgkmcnt(0)" ::: "memory");
  __syncthreads();

  for (int kt = 0; kt < NKT; ++kt) {
    const int buf = kt & 1;
    const unsigned aB = (unsigned)(buf * 32768 + wr * 8192 + fr * 64);
    const unsigned bB = (unsigned)(buf * 32768 + 16384 + (wc >> 1) * 8192 +
                                   ((wc & 1) * 64 + fr) * 64);
#pragma unroll
    for (int ph = 0; ph < 4; ++ph) {
      const int mh = ph >> 1, nh = ph & 1;
      bf16x8 af[4][2], bfr[2][2];
#pragma unroll
      for (int mm = 0; mm < 4; ++mm) {
        const unsigned r = aB + (unsigned)((mh * 4 + mm) * 1024);
        af[mm][0] = *(const bf16x8*)&S[r + cbE0];
        af[mm][1] = *(const bf16x8*)&S[r + cbE1];
      }
#pragma unroll
      for (int nn = 0; nn < 2; ++nn) {
        const unsigned r = bB + (unsigned)((nh * 2 + nn) * 1024);
        bfr[nn][0] = *(const bf16x8*)&S[r + cbE0];
        bfr[nn][1] = *(const bf16x8*)&S[r + cbE1];
      }
      if (ph == 0 && kt + 1 < NKT) {
        if constexpr (AF32) ALOAD_ALL(kt + 1);
        BSTAGE(kt + 1, buf ^ 1);
        if constexpr (!AF32) ASTAGE(kt + 1, buf ^ 1);
      }
      if constexpr (AF32) {
        if (ph == 2 && kt + 1 < NKT) AWRITE_ALL(buf ^ 1);
      }
      __builtin_amdgcn_s_barrier();
      __builtin_amdgcn_s_setprio(1);
#pragma unroll
      for (int mm = 0; mm < 4; ++mm)
#pragma unroll
        for (int nn = 0; nn < 2; ++nn) {
          acc[mh * 4 + mm][nh * 2 + nn] = __builtin_amdgcn_mfma_f32_16x16x32_bf16(
              af[mm][0], bfr[nn][0], acc[mh * 4 + mm][nh * 2 + nn], 0, 0, 0);
          acc[mh * 4 + mm][nh * 2 + nn] = __builtin_amdgcn_mfma_f32_16x16x32_bf16(
              af[mm][1], bfr[nn][1], acc[mh * 4 + mm][nh * 2 + nn], 0, 0, 0);
        }
      __builtin_amdgcn_s_setprio(0);
      if (ph == 3) {
        if constexpr (AF32) {
          asm volatile("s_waitcnt lgkmcnt(0)" ::: "memory");
          __builtin_amdgcn_sched_barrier(0);
        }
        asm volatile("s_waitcnt vmcnt(0)" ::: "memory");
      }
      __builtin_amdgcn_s_barrier();
    }
  }
#undef BSTAGE
#undef ASTAGE
#undef ALOAD_ALL
#undef AWRITE_ALL

  const int rowb = m0 + wr * 128 + fq * 4;
  const int colb = n0 + wc * 64 + fr;
  if constexpr (MODE == 3) {
    unsigned short* Kx = (unsigned short*)out;
    float bb4[4];
#pragma unroll
    for (int nq = 0; nq < 4; ++nq) bb4[nq] = bias[colb + nq * 16];
#pragma unroll
    for (int mq = 0; mq < 8; ++mq) {
      const int ibase = rowb + mq * 16;
      const int b = ibase >> 12, lb = ibase & 4095;
      float sv0, cv0, sv1, cv1, sv2, cv2, sv3, cv3;
      __sincosf(PI_F * (float)(lb + 1) * (1.0f / 8192.0f), &sv0, &cv0);
      __sincosf(PI_F * (float)(lb + 2) * (1.0f / 8192.0f), &sv1, &cv1);
      __sincosf(PI_F * (float)(lb + 3) * (1.0f / 8192.0f), &sv2, &cv2);
      __sincosf(PI_F * (float)(lb + 4) * (1.0f / 8192.0f), &sv3, &cv3);
#pragma unroll
      for (int nq = 0; nq < 4; ++nq) {
        const int col = colb + nq * 16;
        const int h = col >> 6, dd = col & 63;
        const float v0 = fmaxf(acc[mq][nq][0] + bb4[nq], 0.0f);
        const float v1 = fmaxf(acc[mq][nq][1] + bb4[nq], 0.0f);
        const float v2 = fmaxf(acc[mq][nq][2] + bb4[nq], 0.0f);
        const float v3 = fmaxf(acc[mq][nq][3] + bb4[nq], 0.0f);
        uint2 us, uc;
        us.x = (unsigned)f2bf(v0 * sv0) | ((unsigned)f2bf(v1 * sv1) << 16);
        us.y = (unsigned)f2bf(v2 * sv2) | ((unsigned)f2bf(v3 * sv3) << 16);
        uc.x = (unsigned)f2bf(v0 * cv0) | ((unsigned)f2bf(v1 * cv1) << 16);
        uc.y = (unsigned)f2bf(v2 * cv2) | ((unsigned)f2bf(v3 * cv3) << 16);
        const size_t kb_ = ((size_t)((b << 4) + h) * 128 + dd) * 4096 + lb;
        *(uint2*)(Kx + kb_) = us;
        *(uint2*)(Kx + kb_ + (size_t)64 * 4096) = uc;
      }
    }
  } else if constexpr (MODE == 4) {
    unsigned short* Vt = (unsigned short*)out;
    float bb4[4];
#pragma unroll
    for (int nq = 0; nq < 4; ++nq) bb4[nq] = bias[colb + nq * 16];
#pragma unroll
    for (int mq = 0; mq < 8; ++mq) {
      const int ibase = rowb + mq * 16;
      const int b = ibase >> 12, lb = ibase & 4095;
#pragma unroll
      for (int nq = 0; nq < 4; ++nq) {
        const int col = colb + nq * 16;
        const int h = col >> 6, dd = col & 63;
        const float v0 = acc[mq][nq][0] + bb4[nq];
        const float v1 = acc[mq][nq][1] + bb4[nq];
        const float v2 = acc[mq][nq][2] + bb4[nq];
        const float v3 = acc[mq][nq][3] + bb4[nq];
        uint2 uv;
        uv.x = (unsigned)f2bf(v0) | ((unsigned)f2bf(v1) << 16);
        uv.y = (unsigned)f2bf(v2) | ((unsigned)f2bf(v3) << 16);
        const size_t vb_ = ((size_t)((b << 4) + h) * 64 + dd) * 4096 + lb;
        *(uint2*)(Vt + vb_) = uv;
      }
    }
  } else {
#pragma unroll
    for (int nq = 0; nq < 4; ++nq) {
      const int col = colb + nq * 16;
      const float bb = bias[col];
#pragma unroll
      for (int mq = 0; mq < 8; ++mq) {
#pragma unroll
        for (int rr = 0; rr < 4; ++rr) {
          const int i = rowb + mq * 16 + rr;
          float val = acc[mq][nq][rr] + bb;
          if constexpr (MODE == 0) val = fmaxf(val, 0.0f);
          if constexpr (MODE == 2) {
            ((float*)out)[(size_t)i * 1024 + col] = val;
          } else {
            const int b = i >> 12, l = i & 4095, h = col >> 6, dd = col & 63;
            ((unsigned short*)out)[((size_t)((b << 4) + h) * 4096 + l) * 64 + dd] = f2bf(val);
          }
        }
      }
    }
  }
}

// ---------------- k3: kv partial GEMM via MFMA ----------------
__global__ __launch_bounds__(256, 2) void kv_gemm(
    const unsigned short* __restrict__ Vt,   // [64][64][4096]
    const unsigned short* __restrict__ Kx,   // [64][128][4096]
    float* __restrict__ kvp) {               // [64*8][65][128]
  __shared__ unsigned short As[64 * 64];
  __shared__ unsigned short Bs[128 * 64];
  const int tid = threadIdx.x, wave = tid >> 6, lane = tid & 63;
  const int fr = lane & 15, fq = lane >> 4;
  const int ls = blockIdx.x, bh = blockIdx.y;
  const size_t vbase = (size_t)bh * 64 * 4096;
  const size_t kbase = (size_t)bh * 128 * 4096;
  f32x4 acc[5][2] = {};
  bf16x8 ones;
#pragma unroll
  for (int j = 0; j < 8; ++j) ones[j] = (__bf16)1.0f;
  for (int t = 0; t < 8; ++t) {
    const int l0 = ls * 512 + t * 64;
    __syncthreads();
#pragma unroll
    for (int j = 0; j < 2; ++j) {
      const int p = j * 256 + tid;
      const int row = p >> 3, cc = (p & 7) ^ (row & 7);
      GLD16(Vt + vbase + (size_t)row * 4096 + l0 + cc * 8,
            As + ((j << 8) + (wave << 6)) * 8);
    }
#pragma unroll
    for (int j = 0; j < 4; ++j) {
      const int p = j * 256 + tid;
      const int row = p >> 3, cc = (p & 7) ^ (row & 7);
      GLD16(Kx + kbase + (size_t)row * 4096 + l0 + cc * 8,
            Bs + ((j << 8) + (wave << 6)) * 8);
    }
    __syncthreads();
#pragma unroll
    for (int kk = 0; kk < 2; ++kk) {
      const int ch = kk * 4 + fq;
      bf16x8 a[4], b[2];
#pragma unroll
      for (int m = 0; m < 4; ++m) {
        const int r = m * 16 + fr;
        a[m] = *(const bf16x8*)&As[(r * 8 + (ch ^ (r & 7))) * 8];
      }
#pragma unroll
      for (int n = 0; n < 2; ++n) {
        const int r = wave * 32 + n * 16 + fr;
        b[n] = *(const bf16x8*)&Bs[(r * 8 + (ch ^ (r & 7))) * 8];
      }
#pragma unroll
      for (int m = 0; m < 4; ++m)
#pragma unroll
        for (int n = 0; n < 2; ++n)
          acc[m][n] = __builtin_amdgcn_mfma_f32_16x16x32_bf16(a[m], b[n], acc[m][n], 0, 0, 0);
#pragma unroll
      for (int n = 0; n < 2; ++n)
        acc[4][n] = __builtin_amdgcn_mfma_f32_16x16x32_bf16(ones, b[n], acc[4][n], 0, 0, 0);
    }
  }
  float* outp = kvp + ((size_t)bh * 8 + ls) * (65 * 128);
  const int colb = wave * 32 + fr;
#pragma unroll
  for (int n = 0; n < 2; ++n) {
    const int col = colb + n * 16;
#pragma unroll
    for (int m = 0; m < 4; ++m)
#pragma unroll
      for (int r = 0; r < 4; ++r)
        outp[(m * 16 + fq * 4 + r) * 128 + col] = acc[m][n][r];
    if (fq == 0) outp[64 * 128 + col] = acc[4][n][0];
  }
}

// ---------------- k3b: reduce partials -> kv_ext bf16 [bh][80][128] ----------------
__global__ __launch_bounds__(256) void kv_reduce(
    const float* __restrict__ kvp, unsigned short* __restrict__ kv_ext) {
  const int bh = blockIdx.x;
  for (int e = threadIdx.x; e < 80 * 128; e += 256) {
    const int row = e >> 7, c = e & 127;
    float v = 0.0f;
    if (row < 65) {
#pragma unroll
      for (int ls = 0; ls < 8; ++ls)
        v += kvp[((size_t)bh * 8 + ls) * (65 * 128) + row * 128 + c];
    }
    kv_ext[(size_t)bh * (80 * 128) + e] = f2bf(v);
  }
}

// ---------------- k4: attn = (q_ @ kv) / max(q_ . ksum, eps) ----------------
__global__ __launch_bounds__(256) void attn_phase2(
    const unsigned short* __restrict__ Qh, const unsigned short* __restrict__ kve,
    unsigned short* __restrict__ attn) {
  __shared__ unsigned short Qs[128 * 128];
  __shared__ unsigned short Ws[80 * 128];
  const int tid = threadIdx.x, wave = tid >> 6, lane = tid & 63;
  const int fr = lane & 15, fq = lane >> 4;
  const int l0 = blockIdx.x * 128;
  const int bh = blockIdx.y, b = bh >> 4, h = bh & 15;
#pragma unroll
  for (int j = 0; j < 5; ++j) {
    const int p = j * 256 + tid;
    const int r = p >> 4, scn = p & 15;
    const int cc = scn ^ (r & 7);
    GLD16(kve + ((size_t)bh * 80 + r) * 128 + cc * 8,
          Ws + ((size_t)(j * 256 + wave * 64)) * 8);
  }
#pragma unroll
  for (int it = 0; it < 4; ++it) {
    const int qc = it * 256 + tid;
    const int r = qc >> 3, dc = qc & 7;
    const uint4 w = *(const uint4*)(Qh + ((size_t)bh * 4096 + l0 + r) * 64 + dc * 8);
    float sv, cv;
    __sincosf(PI_F * (float)(l0 + r + 1) * (1.0f / 8192.0f), &sv, &cv);
    uint4 osn, ocs;
    osn.x = scale_pair(w.x, sv); osn.y = scale_pair(w.y, sv);
    osn.z = scale_pair(w.z, sv); osn.w = scale_pair(w.w, sv);
    ocs.x = scale_pair(w.x, cv); ocs.y = scale_pair(w.y, cv);
    ocs.z = scale_pair(w.z, cv); ocs.w = scale_pair(w.w, cv);
    const int ps = r * 16 + (dc ^ (r & 7));
    *(uint4*)&Qs[ps * 8] = osn;
    *(uint4*)&Qs[(ps + 8) * 8] = ocs;
  }
  __syncthreads();
  f32x4 acc[2][5] = {};
#pragma unroll
  for (int kk = 0; kk < 4; ++kk) {
    const int cc = kk * 4 + fq;
    bf16x8 a[2], bb[5];
#pragma unroll
    for (int m = 0; m < 2; ++m) {
      const int r = wave * 32 + m * 16 + fr;
      a[m] = *(const bf16x8*)&Qs[(r * 16 + (cc ^ (r & 7))) * 8];
    }
#pragma unroll
    for (int n = 0; n < 5; ++n) {
      const int r = n * 16 + fr;
      bb[n] = *(const bf16x8*)&Ws[(r * 16 + (cc ^ (r & 7))) * 8];
    }
#pragma unroll
    for (int m = 0; m < 2; ++m)
#pragma unroll
      for (int n = 0; n < 5; ++n)
        acc[m][n] = __builtin_amdgcn_mfma_f32_16x16x32_bf16(a[m], bb[n], acc[m][n], 0, 0, 0);
  }
#pragma unroll
  for (int m = 0; m < 2; ++m) {
#pragma unroll
    for (int r = 0; r < 4; ++r) {
      const float den = __shfl(acc[m][4][r], lane & 48);
      const float z = 1.0f / fmaxf(den, 1e-6f);
      const int l = l0 + wave * 32 + m * 16 + fq * 4 + r;
      const size_t ro = ((size_t)b * 4096 + l) * 1024 + (size_t)h * 64;
#pragma unroll
      for (int n = 0; n < 4; ++n)
        attn[ro + n * 16 + fr] = f2bf(acc[m][n][r] * z);
    }
  }
}

// ---------------- launch ----------------
extern "C" void kernel_launch(void* const* d_in, const int* in_sizes, int n_in,
                              void* d_out, int out_size, void* d_ws, size_t ws_size,
                              hipStream_t stream) {
  (void)in_sizes; (void)n_in; (void)out_size; (void)ws_size;
  const float* q  = (const float*)d_in[0];
  const float* k  = (const float*)d_in[1];
  const float* v  = (const float*)d_in[2];
  const float* Wq = (const float*)d_in[3];
  const float* bq = (const float*)d_in[4];
  const float* Wk = (const float*)d_in[5];
  const float* bk = (const float*)d_in[6];
  const float* Wv = (const float*)d_in[7];
  const float* bvp = (const float*)d_in[8];
  const float* Wo = (const float*)d_in[9];
  const float* bo = (const float*)d_in[10];

  char* ws = (char*)d_ws;
  unsigned short* Wqb = (unsigned short*)(ws + 0);
  unsigned short* Wkb = (unsigned short*)(ws + 2097152);
  unsigned short* Wvb = (unsigned short*)(ws + 4194304);
  unsigned short* Wob = (unsigned short*)(ws + 6291456);
  unsigned short* Qh  = (unsigned short*)(ws + 8388608);    // [bh][4096][64] bf16, 32 MB
  unsigned short* Vt  = (unsigned short*)(ws + 41943040);   // [bh][64][4096] bf16, 32 MB
  unsigned short* attnb = (unsigned short*)(ws + 75497472); // [B,L,1024] bf16, 32 MB
  float* kvp          = (float*)(ws + 109051904);           // [512][65][128] f32
  unsigned short* kve = (unsigned short*)(ws + 126091264);  // [64][80][128] bf16
  unsigned short* Kx  = (unsigned short*)d_out;             // K_ext [bh][128][4096], 64 MB

  convert_w<<<dim3(128, 4), 256, 0, stream>>>(Wq, Wk, Wv, Wo, Wqb, Wkb, Wvb, Wob);
  gemm256<0, true><<<256, 512, 0, stream>>>(q, Wqb, bq, Qh);
  gemm256<3, true><<<256, 512, 0, stream>>>(k, Wkb, bk, Kx);
  gemm256<4, true><<<256, 512, 0, stream>>>(v, Wvb, bvp, Vt);
  kv_gemm<<<dim3(8, 64), 256, 0, stream>>>(Vt, Kx, kvp);
  kv_reduce<<<64, 256, 0, stream>>>(kvp, kve);
  attn_phase2<<<dim3(32, 64), 256, 0, stream>>>(Qh, kve, attnb);
  gemm256<2, false><<<256, 512, 0, stream>>>(attnb, Wob, bo, (float*)d_out);
}

// Round 5
// 295.085 us; speedup vs baseline: 1.3681x; 1.0430x over previous
//
#include <hip/hip_runtime.h>

typedef __bf16 bf16x8 __attribute__((ext_vector_type(8)));
typedef float f32x4 __attribute__((ext_vector_type(4)));

#define PI_F 3.14159265358979323846f

__device__ __forceinline__ unsigned short f2bf(float f) {
  unsigned u = __builtin_bit_cast(unsigned, f);
  u += 0x7fffu + ((u >> 16) & 1u);
  return (unsigned short)(u >> 16);
}

__device__ __forceinline__ unsigned scale_pair(unsigned w, float f) {
  const float lo = __builtin_bit_cast(float, w << 16);
  const float hi = __builtin_bit_cast(float, w & 0xffff0000u);
  return (unsigned)f2bf(lo * f) | ((unsigned)f2bf(hi * f) << 16);
}

#define GLD16(gp, lp)                                          \
  __builtin_amdgcn_global_load_lds(                            \
      (const __attribute__((address_space(1))) void*)(gp),     \
      (__attribute__((address_space(3))) void*)(lp), 16, 0, 0)

struct AReg { float4 a0, a1, a2, a3, a4, a5, a6, a7; };

__device__ __forceinline__ uint4 cvtpk16(float4 x, float4 y) {
  unsigned c0, c1, c2, c3;
  asm("v_cvt_pk_bf16_f32 %0, %1, %2" : "=v"(c0) : "v"(x.x), "v"(x.y));
  asm("v_cvt_pk_bf16_f32 %0, %1, %2" : "=v"(c1) : "v"(x.z), "v"(x.w));
  asm("v_cvt_pk_bf16_f32 %0, %1, %2" : "=v"(c2) : "v"(y.x), "v"(y.y));
  asm("v_cvt_pk_bf16_f32 %0, %1, %2" : "=v"(c3) : "v"(y.z), "v"(y.w));
  uint4 u; u.x = c0; u.y = c1; u.z = c2; u.w = c3;
  return u;
}

__device__ __forceinline__ uint2 cvtpk8(float a, float b, float c, float d) {
  unsigned lo, hi;
  asm("v_cvt_pk_bf16_f32 %0, %1, %2" : "=v"(lo) : "v"(a), "v"(b));
  asm("v_cvt_pk_bf16_f32 %0, %1, %2" : "=v"(hi) : "v"(c), "v"(d));
  uint2 r; r.x = lo; r.y = hi;
  return r;
}

// ---------------- k1: weight fp32 -> bf16 conversion (weights only) ----------------
__global__ __launch_bounds__(256) void convert_w(
    const float* __restrict__ Wq, const float* __restrict__ Wk,
    const float* __restrict__ Wv, const float* __restrict__ Wo,
    unsigned short* __restrict__ Wqb, unsigned short* __restrict__ Wkb,
    unsigned short* __restrict__ Wvb, unsigned short* __restrict__ Wob) {
  const int region = blockIdx.y;
  const float* s; unsigned short* d;
  switch (region) {
    case 0: s = Wq; d = Wqb; break;
    case 1: s = Wk; d = Wkb; break;
    case 2: s = Wv; d = Wvb; break;
    default: s = Wo; d = Wob; break;
  }
  const float4* s4 = (const float4*)s;
  ushort4* d4 = (ushort4*)d;
  const int n4 = 262144;
  for (int i = blockIdx.x * 256 + threadIdx.x; i < n4; i += gridDim.x * 256) {
    float4 f = s4[i];
    ushort4 o;
    o.x = f2bf(f.x); o.y = f2bf(f.y); o.z = f2bf(f.z); o.w = f2bf(f.w);
    d4[i] = o;
  }
}

// ---------------- 256x256 8-phase bf16 GEMM, C = A @ B^T + bias ----------------
// A: 16384 x 1024 row-major (fp32 if AF32, else bf16); Bw: 1024 x 1024 bf16.
// MODE 0: relu, permuted bf16 store (B,H,L,64)              -- Q proj
// MODE 2: fp32 plain row-major                               -- output proj
// MODE 3: relu, sin/cos expanded transposed K_ext[bh][128][4096] bf16
// MODE 4: no relu, transposed Vt[bh][64][4096] bf16
// MODE 0/3/4 epilogues go through an LDS transpose (S reused, 256x256 bf16
// tile fits the 128 KiB exactly) so global stores are 128-512B runs.
template <int MODE, bool AF32>
__global__ __launch_bounds__(512, 2) void gemm256(
    const void* __restrict__ Ain, const unsigned short* __restrict__ Bw,
    const float* __restrict__ bias, void* __restrict__ out) {
  constexpr int K = 1024, NKT = 16;
  __shared__ unsigned short S[65536];  // [buf:32768][A:16384|B:16384]
  const int tid = threadIdx.x;
  const int wave = tid >> 6, lane = tid & 63;
  const int fr = lane & 15, fq = lane >> 4;
  const int wr = wave >> 2, wc = wave & 3;
  const int cpx = gridDim.x >> 3;
  const int wg = (blockIdx.x & 7) * cpx + (blockIdx.x >> 3);
  const int mt = wg >> 2, ntile = wg & 3;
  const int m0 = mt * 256, n0 = ntile * 256;

  // staging thread mapping: srow = row-in-64-group, 16B chunk ac16
  const int srow = tid >> 3;
  const int ac16 = tid & 7;
  const int scolE = ((ac16 << 4) ^ ((srow & 7) << 4)) >> 1;  // pre-swizzled src col (elems)
  const unsigned short* bSrc = Bw + (size_t)(n0 + srow) * K + scolE;
  const unsigned short* aSrcB =
      AF32 ? (const unsigned short*)nullptr
           : ((const unsigned short*)Ain + (size_t)(m0 + srow) * K + scolE);
  const float* A32 = (const float*)Ain;
  const int awoff = (ac16 ^ (srow & 7)) << 3;  // swizzled dst chunk (elems)
  AReg R;

#define BSTAGE(kt_, buf_) do {                                                     \
    const int kc_ = (kt_) * 64;                                                    \
    GLD16(bSrc + kc_,                  S + (buf_) * 32768 + 16384 + wave * 512);   \
    GLD16(bSrc + (size_t)65536 + kc_,  S + (buf_) * 32768 + 20480 + wave * 512);   \
    GLD16(bSrc + (size_t)131072 + kc_, S + (buf_) * 32768 + 24576 + wave * 512);   \
    GLD16(bSrc + (size_t)196608 + kc_, S + (buf_) * 32768 + 28672 + wave * 512);   \
  } while (0)

#define ASTAGE(kt_, buf_) do {                                                     \
    const int kc_ = (kt_) * 64;                                                    \
    GLD16(aSrcB + kc_,                  S + (buf_) * 32768 +     0 + wave * 512);  \
    GLD16(aSrcB + (size_t)65536 + kc_,  S + (buf_) * 32768 +  4096 + wave * 512);  \
    GLD16(aSrcB + (size_t)131072 + kc_, S + (buf_) * 32768 +  8192 + wave * 512);  \
    GLD16(aSrcB + (size_t)196608 + kc_, S + (buf_) * 32768 + 12288 + wave * 512);  \
  } while (0)

#define ALOAD_ALL(kt_) do {                                                        \
    const int kc_ = (kt_) * 64;                                                    \
    const float4* p_;                                                              \
    p_ = (const float4*)(A32 + (size_t)(m0 + srow) * K + kc_) + ac16 * 2;          \
    R.a0 = p_[0]; R.a1 = p_[1];                                                    \
    p_ = (const float4*)(A32 + (size_t)(m0 + 64 + srow) * K + kc_) + ac16 * 2;     \
    R.a2 = p_[0]; R.a3 = p_[1];                                                    \
    p_ = (const float4*)(A32 + (size_t)(m0 + 128 + srow) * K + kc_) + ac16 * 2;    \
    R.a4 = p_[0]; R.a5 = p_[1];                                                    \
    p_ = (const float4*)(A32 + (size_t)(m0 + 192 + srow) * K + kc_) + ac16 * 2;    \
    R.a6 = p_[0]; R.a7 = p_[1];                                                    \
  } while (0)

#define AWRITE_ALL(buf_) do {                                                      \
    unsigned short* dst_ = &S[(buf_) * 32768 + srow * 64 + awoff];                 \
    *(uint4*)(dst_)         = cvtpk16(R.a0, R.a1);                                 \
    *(uint4*)(dst_ + 4096)  = cvtpk16(R.a2, R.a3);                                 \
    *(uint4*)(dst_ + 8192)  = cvtpk16(R.a4, R.a5);                                 \
    *(uint4*)(dst_ + 12288) = cvtpk16(R.a6, R.a7);                                 \
  } while (0)

  // ds_read lane constants
  const int xorv = (fr & 7) << 4;
  const unsigned cbE0 = (unsigned)(((fq * 16) ^ xorv) >> 1);
  const unsigned cbE1 = (unsigned)(((64 + fq * 16) ^ xorv) >> 1);

  f32x4 acc[8][4] = {};
  if constexpr (AF32) {
    ALOAD_ALL(0);
    BSTAGE(0, 0);
    AWRITE_ALL(0);
  } else {
    BSTAGE(0, 0);
    ASTAGE(0, 0);
  }
  asm volatile("s_waitcnt vmcnt(0) lgkmcnt(0)" ::: "memory");
  __syncthreads();

  for (int kt = 0; kt < NKT; ++kt) {
    const int buf = kt & 1;
    const unsigned aB = (unsigned)(buf * 32768 + wr * 8192 + fr * 64);
    const unsigned bB = (unsigned)(buf * 32768 + 16384 + (wc >> 1) * 8192 +
                                   ((wc & 1) * 64 + fr) * 64);
#pragma unroll
    for (int ph = 0; ph < 4; ++ph) {
      const int mh = ph >> 1, nh = ph & 1;
      bf16x8 af[4][2], bfr[2][2];
#pragma unroll
      for (int mm = 0; mm < 4; ++mm) {
        const unsigned r = aB + (unsigned)((mh * 4 + mm) * 1024);
        af[mm][0] = *(const bf16x8*)&S[r + cbE0];
        af[mm][1] = *(const bf16x8*)&S[r + cbE1];
      }
#pragma unroll
      for (int nn = 0; nn < 2; ++nn) {
        const unsigned r = bB + (unsigned)((nh * 2 + nn) * 1024);
        bfr[nn][0] = *(const bf16x8*)&S[r + cbE0];
        bfr[nn][1] = *(const bf16x8*)&S[r + cbE1];
      }
      if (ph == 0 && kt + 1 < NKT) {
        if constexpr (AF32) ALOAD_ALL(kt + 1);
        BSTAGE(kt + 1, buf ^ 1);
        if constexpr (!AF32) ASTAGE(kt + 1, buf ^ 1);
      }
      if constexpr (AF32) {
        if (ph == 2 && kt + 1 < NKT) AWRITE_ALL(buf ^ 1);
      }
      __builtin_amdgcn_s_barrier();
      __builtin_amdgcn_s_setprio(1);
#pragma unroll
      for (int mm = 0; mm < 4; ++mm)
#pragma unroll
        for (int nn = 0; nn < 2; ++nn) {
          acc[mh * 4 + mm][nh * 2 + nn] = __builtin_amdgcn_mfma_f32_16x16x32_bf16(
              af[mm][0], bfr[nn][0], acc[mh * 4 + mm][nh * 2 + nn], 0, 0, 0);
          acc[mh * 4 + mm][nh * 2 + nn] = __builtin_amdgcn_mfma_f32_16x16x32_bf16(
              af[mm][1], bfr[nn][1], acc[mh * 4 + mm][nh * 2 + nn], 0, 0, 0);
        }
      __builtin_amdgcn_s_setprio(0);
      if (ph == 3) {
        if constexpr (AF32) {
          asm volatile("s_waitcnt lgkmcnt(0)" ::: "memory");
          __builtin_amdgcn_sched_barrier(0);
        }
        asm volatile("s_waitcnt vmcnt(0)" ::: "memory");
      }
      __builtin_amdgcn_s_barrier();
    }
  }
#undef BSTAGE
#undef ASTAGE
#undef ALOAD_ALL
#undef AWRITE_ALL

  const int rowb = m0 + wr * 128 + fq * 4;
  const int colb = n0 + wc * 64 + fr;
  const int rtb0 = wr * 128 + fq * 4;
  const int mlo = m0 & 4095;
  const int b16 = ((m0 >> 12) << 4);
  const int hbase = n0 >> 6;

  if constexpr (MODE == 2) {
#pragma unroll
    for (int nq = 0; nq < 4; ++nq) {
      const int col = colb + nq * 16;
      const float bb = bias[col];
#pragma unroll
      for (int mq = 0; mq < 8; ++mq) {
#pragma unroll
        for (int rr = 0; rr < 4; ++rr) {
          const int i = rowb + mq * 16 + rr;
          ((float*)out)[(size_t)i * 1024 + col] = acc[mq][nq][rr] + bb;
        }
      }
    }
  } else if constexpr (MODE == 0) {
    // finalize: relu(acc + bias)
    float bb4[4];
#pragma unroll
    for (int nq = 0; nq < 4; ++nq) bb4[nq] = bias[colb + nq * 16];
#pragma unroll
    for (int mq = 0; mq < 8; ++mq)
#pragma unroll
      for (int nq = 0; nq < 4; ++nq)
#pragma unroll
        for (int rr = 0; rr < 4; ++rr)
          acc[mq][nq][rr] = fmaxf(acc[mq][nq][rr] + bb4[nq], 0.0f);
    __syncthreads();
    // LDS row-major [rt][ct ^ ((rt&7)<<2)], scalar writes
#pragma unroll
    for (int mq = 0; mq < 8; ++mq) {
      const int rtb = rtb0 + mq * 16;
#pragma unroll
      for (int rr = 0; rr < 4; ++rr) {
        const int rt = rtb + rr;
        const int sw = (rt & 7) << 2;
#pragma unroll
        for (int nq = 0; nq < 4; ++nq) {
          const int ct = wc * 64 + nq * 16 + fr;
          S[rt * 256 + (ct ^ sw)] = f2bf(acc[mq][nq][rr]);
        }
      }
    }
    __syncthreads();
    unsigned short* G = (unsigned short*)out;
#pragma unroll
    for (int it = 0; it < 16; ++it) {
      const int rt = it * 16 + (tid >> 5);
      const int co = (tid & 31) << 3;
      const int sw = (rt & 7) << 2;
      uint2 r0 = *(const uint2*)&S[rt * 256 + (co ^ sw)];
      uint2 r1 = *(const uint2*)&S[rt * 256 + ((co + 4) ^ sw)];
      uint4 w; w.x = r0.x; w.y = r0.y; w.z = r1.x; w.w = r1.y;
      const int h = hbase + (co >> 6), dd = co & 63;
      const size_t addr = ((size_t)(b16 + h) * 4096 + mlo + rt) * 64 + dd;
      *(uint4*)(G + addr) = w;
    }
  } else {
    // MODE 3 / MODE 4: LDS col-major [ct][rt ^ ((ct&7)<<2)], vectorized b64 writes
    float bb4[4];
#pragma unroll
    for (int nq = 0; nq < 4; ++nq) bb4[nq] = bias[colb + nq * 16];
#pragma unroll
    for (int mq = 0; mq < 8; ++mq)
#pragma unroll
      for (int nq = 0; nq < 4; ++nq)
#pragma unroll
        for (int rr = 0; rr < 4; ++rr) {
          float val = acc[mq][nq][rr] + bb4[nq];
          if constexpr (MODE == 3) val = fmaxf(val, 0.0f);
          acc[mq][nq][rr] = val;
        }
    unsigned short* G = (unsigned short*)out;
    constexpr int NPASS = (MODE == 3) ? 2 : 1;
#pragma unroll
    for (int p = 0; p < NPASS; ++p) {
      __syncthreads();
#pragma unroll
      for (int mq = 0; mq < 8; ++mq) {
        const int rtb = rtb0 + mq * 16;
        float s0 = 1.0f, s1 = 1.0f, s2 = 1.0f, s3 = 1.0f;
        if constexpr (MODE == 3) {
          float sv, cv;
          __sincosf(PI_F * (float)(mlo + rtb + 1) * (1.0f / 8192.0f), &sv, &cv);
          s0 = p ? cv : sv;
          __sincosf(PI_F * (float)(mlo + rtb + 2) * (1.0f / 8192.0f), &sv, &cv);
          s1 = p ? cv : sv;
          __sincosf(PI_F * (float)(mlo + rtb + 3) * (1.0f / 8192.0f), &sv, &cv);
          s2 = p ? cv : sv;
          __sincosf(PI_F * (float)(mlo + rtb + 4) * (1.0f / 8192.0f), &sv, &cv);
          s3 = p ? cv : sv;
        }
#pragma unroll
        for (int nq = 0; nq < 4; ++nq) {
          const int ct = wc * 64 + nq * 16 + fr;
          uint2 w;
          if constexpr (MODE == 3)
            w = cvtpk8(acc[mq][nq][0] * s0, acc[mq][nq][1] * s1,
                       acc[mq][nq][2] * s2, acc[mq][nq][3] * s3);
          else
            w = cvtpk8(acc[mq][nq][0], acc[mq][nq][1], acc[mq][nq][2], acc[mq][nq][3]);
          *(uint2*)&S[ct * 256 + (rtb ^ ((ct & 7) << 2))] = w;
        }
      }
      __syncthreads();
#pragma unroll
      for (int it = 0; it < 16; ++it) {
        const int ct = it * 16 + (tid >> 5);
        const int lo = (tid & 31) << 3;
        const int sw = (ct & 7) << 2;
        uint2 r0 = *(const uint2*)&S[ct * 256 + (lo ^ sw)];
        uint2 r1 = *(const uint2*)&S[ct * 256 + ((lo + 4) ^ sw)];
        uint4 w; w.x = r0.x; w.y = r0.y; w.z = r1.x; w.w = r1.y;
        const int h = hbase + (ct >> 6), dd = ct & 63;
        size_t addr;
        if constexpr (MODE == 3)
          addr = ((size_t)(b16 + h) * 128 + dd + p * 64) * 4096 + mlo + lo;
        else
          addr = ((size_t)(b16 + h) * 64 + dd) * 4096 + mlo + lo;
        *(uint4*)(G + addr) = w;
      }
    }
  }
}

// ---------------- k3: kv partial GEMM via MFMA ----------------
__global__ __launch_bounds__(256, 2) void kv_gemm(
    const unsigned short* __restrict__ Vt,   // [64][64][4096]
    const unsigned short* __restrict__ Kx,   // [64][128][4096]
    float* __restrict__ kvp) {               // [64*8][65][128]
  __shared__ unsigned short As[64 * 64];
  __shared__ unsigned short Bs[128 * 64];
  const int tid = threadIdx.x, wave = tid >> 6, lane = tid & 63;
  const int fr = lane & 15, fq = lane >> 4;
  const int ls = blockIdx.x, bh = blockIdx.y;
  const size_t vbase = (size_t)bh * 64 * 4096;
  const size_t kbase = (size_t)bh * 128 * 4096;
  f32x4 acc[5][2] = {};
  bf16x8 ones;
#pragma unroll
  for (int j = 0; j < 8; ++j) ones[j] = (__bf16)1.0f;
  for (int t = 0; t < 8; ++t) {
    const int l0 = ls * 512 + t * 64;
    __syncthreads();
#pragma unroll
    for (int j = 0; j < 2; ++j) {
      const int p = j * 256 + tid;
      const int row = p >> 3, cc = (p & 7) ^ (row & 7);
      GLD16(Vt + vbase + (size_t)row * 4096 + l0 + cc * 8,
            As + ((j << 8) + (wave << 6)) * 8);
    }
#pragma unroll
    for (int j = 0; j < 4; ++j) {
      const int p = j * 256 + tid;
      const int row = p >> 3, cc = (p & 7) ^ (row & 7);
      GLD16(Kx + kbase + (size_t)row * 4096 + l0 + cc * 8,
            Bs + ((j << 8) + (wave << 6)) * 8);
    }
    __syncthreads();
#pragma unroll
    for (int kk = 0; kk < 2; ++kk) {
      const int ch = kk * 4 + fq;
      bf16x8 a[4], b[2];
#pragma unroll
      for (int m = 0; m < 4; ++m) {
        const int r = m * 16 + fr;
        a[m] = *(const bf16x8*)&As[(r * 8 + (ch ^ (r & 7))) * 8];
      }
#pragma unroll
      for (int n = 0; n < 2; ++n) {
        const int r = wave * 32 + n * 16 + fr;
        b[n] = *(const bf16x8*)&Bs[(r * 8 + (ch ^ (r & 7))) * 8];
      }
#pragma unroll
      for (int m = 0; m < 4; ++m)
#pragma unroll
        for (int n = 0; n < 2; ++n)
          acc[m][n] = __builtin_amdgcn_mfma_f32_16x16x32_bf16(a[m], b[n], acc[m][n], 0, 0, 0);
#pragma unroll
      for (int n = 0; n < 2; ++n)
        acc[4][n] = __builtin_amdgcn_mfma_f32_16x16x32_bf16(ones, b[n], acc[4][n], 0, 0, 0);
    }
  }
  float* outp = kvp + ((size_t)bh * 8 + ls) * (65 * 128);
  const int colb = wave * 32 + fr;
#pragma unroll
  for (int n = 0; n < 2; ++n) {
    const int col = colb + n * 16;
#pragma unroll
    for (int m = 0; m < 4; ++m)
#pragma unroll
      for (int r = 0; r < 4; ++r)
        outp[(m * 16 + fq * 4 + r) * 128 + col] = acc[m][n][r];
    if (fq == 0) outp[64 * 128 + col] = acc[4][n][0];
  }
}

// ---------------- k3b: reduce partials -> kv_ext bf16 [bh][80][128] ----------------
__global__ __launch_bounds__(256) void kv_reduce(
    const float* __restrict__ kvp, unsigned short* __restrict__ kv_ext) {
  const int bh = blockIdx.x;
  for (int e = threadIdx.x; e < 80 * 128; e += 256) {
    const int row = e >> 7, c = e & 127;
    float v = 0.0f;
    if (row < 65) {
#pragma unroll
      for (int ls = 0; ls < 8; ++ls)
        v += kvp[((size_t)bh * 8 + ls) * (65 * 128) + row * 128 + c];
    }
    kv_ext[(size_t)bh * (80 * 128) + e] = f2bf(v);
  }
}

// ---------------- k4: attn = (q_ @ kv) / max(q_ . ksum, eps) ----------------
__global__ __launch_bounds__(256) void attn_phase2(
    const unsigned short* __restrict__ Qh, const unsigned short* __restrict__ kve,
    unsigned short* __restrict__ attn) {
  __shared__ unsigned short Qs[128 * 128];
  __shared__ unsigned short Ws[80 * 128];
  const int tid = threadIdx.x, wave = tid >> 6, lane = tid & 63;
  const int fr = lane & 15, fq = lane >> 4;
  const int l0 = blockIdx.x * 128;
  const int bh = blockIdx.y, b = bh >> 4, h = bh & 15;
#pragma unroll
  for (int j = 0; j < 5; ++j) {
    const int p = j * 256 + tid;
    const int r = p >> 4, scn = p & 15;
    const int cc = scn ^ (r & 7);
    GLD16(kve + ((size_t)bh * 80 + r) * 128 + cc * 8,
          Ws + ((size_t)(j * 256 + wave * 64)) * 8);
  }
#pragma unroll
  for (int it = 0; it < 4; ++it) {
    const int qc = it * 256 + tid;
    const int r = qc >> 3, dc = qc & 7;
    const uint4 w = *(const uint4*)(Qh + ((size_t)bh * 4096 + l0 + r) * 64 + dc * 8);
    float sv, cv;
    __sincosf(PI_F * (float)(l0 + r + 1) * (1.0f / 8192.0f), &sv, &cv);
    uint4 osn, ocs;
    osn.x = scale_pair(w.x, sv); osn.y = scale_pair(w.y, sv);
    osn.z = scale_pair(w.z, sv); osn.w = scale_pair(w.w, sv);
    ocs.x = scale_pair(w.x, cv); ocs.y = scale_pair(w.y, cv);
    ocs.z = scale_pair(w.z, cv); ocs.w = scale_pair(w.w, cv);
    const int ps = r * 16 + (dc ^ (r & 7));
    *(uint4*)&Qs[ps * 8] = osn;
    *(uint4*)&Qs[(ps + 8) * 8] = ocs;
  }
  __syncthreads();
  f32x4 acc[2][5] = {};
#pragma unroll
  for (int kk = 0; kk < 4; ++kk) {
    const int cc = kk * 4 + fq;
    bf16x8 a[2], bb[5];
#pragma unroll
    for (int m = 0; m < 2; ++m) {
      const int r = wave * 32 + m * 16 + fr;
      a[m] = *(const bf16x8*)&Qs[(r * 16 + (cc ^ (r & 7))) * 8];
    }
#pragma unroll
    for (int n = 0; n < 5; ++n) {
      const int r = n * 16 + fr;
      bb[n] = *(const bf16x8*)&Ws[(r * 16 + (cc ^ (r & 7))) * 8];
    }
#pragma unroll
    for (int m = 0; m < 2; ++m)
#pragma unroll
      for (int n = 0; n < 5; ++n)
        acc[m][n] = __builtin_amdgcn_mfma_f32_16x16x32_bf16(a[m], bb[n], acc[m][n], 0, 0, 0);
  }
#pragma unroll
  for (int m = 0; m < 2; ++m) {
#pragma unroll
    for (int r = 0; r < 4; ++r) {
      const float den = __shfl(acc[m][4][r], lane & 48);
      const float z = 1.0f / fmaxf(den, 1e-6f);
      const int l = l0 + wave * 32 + m * 16 + fq * 4 + r;
      const size_t ro = ((size_t)b * 4096 + l) * 1024 + (size_t)h * 64;
#pragma unroll
      for (int n = 0; n < 4; ++n)
        attn[ro + n * 16 + fr] = f2bf(acc[m][n][r] * z);
    }
  }
}

// ---------------- launch ----------------
extern "C" void kernel_launch(void* const* d_in, const int* in_sizes, int n_in,
                              void* d_out, int out_size, void* d_ws, size_t ws_size,
                              hipStream_t stream) {
  (void)in_sizes; (void)n_in; (void)out_size; (void)ws_size;
  const float* q  = (const float*)d_in[0];
  const float* k  = (const float*)d_in[1];
  const float* v  = (const float*)d_in[2];
  const float* Wq = (const float*)d_in[3];
  const float* bq = (const float*)d_in[4];
  const float* Wk = (const float*)d_in[5];
  const float* bk = (const float*)d_in[6];
  const float* Wv = (const float*)d_in[7];
  const float* bvp = (const float*)d_in[8];
  const float* Wo = (const float*)d_in[9];
  const float* bo = (const float*)d_in[10];

  char* ws = (char*)d_ws;
  unsigned short* Wqb = (unsigned short*)(ws + 0);
  unsigned short* Wkb = (unsigned short*)(ws + 2097152);
  unsigned short* Wvb = (unsigned short*)(ws + 4194304);
  unsigned short* Wob = (unsigned short*)(ws + 6291456);
  unsigned short* Qh  = (unsigned short*)(ws + 8388608);    // [bh][4096][64] bf16, 32 MB
  unsigned short* Vt  = (unsigned short*)(ws + 41943040);   // [bh][64][4096] bf16, 32 MB
  unsigned short* attnb = (unsigned short*)(ws + 75497472); // [B,L,1024] bf16, 32 MB
  float* kvp          = (float*)(ws + 109051904);           // [512][65][128] f32
  unsigned short* kve = (unsigned short*)(ws + 126091264);  // [64][80][128] bf16
  unsigned short* Kx  = (unsigned short*)d_out;             // K_ext [bh][128][4096], 64 MB

  convert_w<<<dim3(128, 4), 256, 0, stream>>>(Wq, Wk, Wv, Wo, Wqb, Wkb, Wvb, Wob);
  gemm256<0, true><<<256, 512, 0, stream>>>(q, Wqb, bq, Qh);
  gemm256<3, true><<<256, 512, 0, stream>>>(k, Wkb, bk, Kx);
  gemm256<4, true><<<256, 512, 0, stream>>>(v, Wvb, bvp, Vt);
  kv_gemm<<<dim3(8, 64), 256, 0, stream>>>(Vt, Kx, kvp);
  kv_reduce<<<64, 256, 0, stream>>>(kvp, kve);
  attn_phase2<<<dim3(32, 64), 256, 0, stream>>>(Qh, kve, attnb);
  gemm256<2, false><<<256, 512, 0, stream>>>(attnb, Wob, bo, (float*)d_out);
}